// Round 1
// baseline (1590.396 us; speedup 1.0000x reference)
//
#include <hip/hip_runtime.h>
#include <hip/hip_bf16.h>
#include <cstdint>

// Problem constants
#define BB 2
#define TT 2048
#define DD 1024
#define HH 16
#define HD 64
#define BT (BB*TT)          // 4096
#define QKV_N (3*DD)        // 3072

// ---------------------------------------------------------------------------
// Tiled fp32 GEMM with bias: C[M,N] = A[M,K] @ B[K,N] + bias[N]
// BM=BN=64, BK=16, 256 threads, 4x4 acc per thread.
// ---------------------------------------------------------------------------
__global__ __launch_bounds__(256) void gemm_bias_f32(
    const float* __restrict__ A, const float* __restrict__ Bm,
    const float* __restrict__ bias, float* __restrict__ C,
    int M, int N, int K)
{
    __shared__ float As[64][17];   // [m][k], +1 pad
    __shared__ float Bs[16][64];   // [k][n]

    const int tid = threadIdx.x;
    const int bm = blockIdx.y * 64;
    const int bn = blockIdx.x * 64;
    const int mb = (tid >> 4) << 2;   // 0,4,...,60
    const int nb = (tid & 15) << 2;   // 0,4,...,60

    float acc[4][4] = {};

    for (int k0 = 0; k0 < K; k0 += 16) {
        // Load A tile: 64 rows x 16 k, one float4 per thread (row-major A).
        {
            const int r  = tid >> 2;
            const int kq = (tid & 3) << 2;
            float4 v = *(const float4*)&A[(size_t)(bm + r) * K + k0 + kq];
            As[r][kq + 0] = v.x; As[r][kq + 1] = v.y;
            As[r][kq + 2] = v.z; As[r][kq + 3] = v.w;
        }
        // Load B tile: 16 rows x 64 n, one float4 per thread.
        {
            const int r  = tid >> 4;
            const int nq = (tid & 15) << 2;
            *(float4*)&Bs[r][nq] = *(const float4*)&Bm[(size_t)(k0 + r) * N + bn + nq];
        }
        __syncthreads();

        #pragma unroll
        for (int kk = 0; kk < 16; ++kk) {
            const float a0 = As[mb + 0][kk];
            const float a1 = As[mb + 1][kk];
            const float a2 = As[mb + 2][kk];
            const float a3 = As[mb + 3][kk];
            const float4 b = *(const float4*)&Bs[kk][nb];
            acc[0][0] += a0 * b.x; acc[0][1] += a0 * b.y; acc[0][2] += a0 * b.z; acc[0][3] += a0 * b.w;
            acc[1][0] += a1 * b.x; acc[1][1] += a1 * b.y; acc[1][2] += a1 * b.z; acc[1][3] += a1 * b.w;
            acc[2][0] += a2 * b.x; acc[2][1] += a2 * b.y; acc[2][2] += a2 * b.z; acc[2][3] += a2 * b.w;
            acc[3][0] += a3 * b.x; acc[3][1] += a3 * b.y; acc[3][2] += a3 * b.z; acc[3][3] += a3 * b.w;
        }
        __syncthreads();
    }

    #pragma unroll
    for (int i = 0; i < 4; ++i) {
        #pragma unroll
        for (int j = 0; j < 4; ++j) {
            C[(size_t)(bm + mb + i) * N + bn + nb + j] = acc[i][j] + bias[bn + nb + j];
        }
    }
}

// ---------------------------------------------------------------------------
// In-place RoPE on the QKV buffer [BT, 3*D]; applies to q and k parts only.
// One thread per (bt, which∈{q,k}, h, pair i∈[0,32)).
// ---------------------------------------------------------------------------
__global__ __launch_bounds__(256) void rope_inplace(float* __restrict__ qkv)
{
    const int idx = blockIdx.x * blockDim.x + threadIdx.x;
    const int total = BT * 2 * HH * 32;     // 4,194,304
    if (idx >= total) return;

    const int i  = idx & 31;          // pair index 0..31
    const int h  = (idx >> 5) & 15;   // head
    const int w  = (idx >> 9) & 1;    // 0=q, 1=k
    const int bt = idx >> 10;         // 0..4095
    const int t  = bt & (TT - 1);     // position within sequence

    // rate = 10000^(-i/32); exact 1.0 at i=0.
    const float rate  = powf(10000.0f, -(float)i * (1.0f / 32.0f));
    const float theta = (float)t * rate;
    const float c = cosf(theta);
    const float s = sinf(theta);

    float* p = qkv + (size_t)bt * QKV_N + w * DD + h * HD + i;
    const float x1 = p[0];
    const float x2 = p[32];
    p[0]  = x1 * c - x2 * s;
    p[32] = x1 * s + x2 * c;
}

// ---------------------------------------------------------------------------
// Causal flash attention (fp32). Grid: (T/64, B*H). Block 256.
// 64 q-rows per block; 4 threads per row, each owns 16 of the 64 head dims.
// K/V tiles (64x64 fp32 each) staged in LDS. Online softmax.
// qkv layout: [BT, 3*D]; y layout: [B*T, D] with D index = h*64 + d.
// ---------------------------------------------------------------------------
__global__ __launch_bounds__(256) void attn_causal(
    const float* __restrict__ qkv, float* __restrict__ y)
{
    __shared__ float Ks[64][64];
    __shared__ float Vs[64][64];

    const int bh = blockIdx.y;
    const int b  = bh >> 4;
    const int h  = bh & 15;
    const int q0 = blockIdx.x * 64;
    const int tid = threadIdx.x;
    const int qr = tid >> 2;        // 0..63
    const int g  = tid & 3;         // 0..3 (dim group)
    const int q  = q0 + qr;         // global query index

    // Load q fragment into registers (16 floats).
    float qreg[16];
    {
        const float* qrow = qkv + (size_t)(b * TT + q) * QKV_N + h * HD + g * 16;
        #pragma unroll
        for (int j = 0; j < 16; j += 4) {
            float4 v = *(const float4*)(qrow + j);
            qreg[j] = v.x; qreg[j + 1] = v.y; qreg[j + 2] = v.z; qreg[j + 3] = v.w;
        }
    }

    float m = -1e30f, l = 0.0f;
    float acc[16];
    #pragma unroll
    for (int j = 0; j < 16; ++j) acc[j] = 0.0f;
    const float scale = 0.125f;     // 1/sqrt(64)

    const int ktiles = (q0 >> 6) + 1;
    for (int tk = 0; tk < ktiles; ++tk) {
        const int k0 = tk << 6;
        const float* Kbase = qkv + (size_t)(b * TT + k0) * QKV_N + DD + h * HD;
        const float* Vbase = Kbase + DD;

        // Stage K and V tiles: 1024 float4 each; 4 float4 per thread per tile.
        #pragma unroll
        for (int c = 0; c < 4; ++c) {
            const int fi = tid + c * 256;
            const int r  = fi >> 4;
            const int dq = (fi & 15) << 2;
            *(float4*)&Ks[r][dq] = *(const float4*)(Kbase + (size_t)r * QKV_N + dq);
            *(float4*)&Vs[r][dq] = *(const float4*)(Vbase + (size_t)r * QKV_N + dq);
        }
        __syncthreads();

        const bool diag = (tk == ktiles - 1);
        for (int k = 0; k < 64; ++k) {
            // Partial dot over this thread's 16 dims.
            float part = 0.0f;
            #pragma unroll
            for (int j = 0; j < 16; j += 4) {
                const float4 kv = *(const float4*)&Ks[k][g * 16 + j];
                part += qreg[j] * kv.x + qreg[j + 1] * kv.y
                      + qreg[j + 2] * kv.z + qreg[j + 3] * kv.w;
            }
            // Combine across the 4 threads of this row (adjacent lanes).
            part += __shfl_xor(part, 1);
            part += __shfl_xor(part, 2);

            float s = part * scale;
            if (diag && (k0 + k > q)) s = -1e30f;

            const float mn    = fmaxf(m, s);
            const float alpha = __expf(m - mn);
            const float p     = __expf(s - mn);
            l = l * alpha + p;
            #pragma unroll
            for (int j = 0; j < 16; ++j)
                acc[j] = acc[j] * alpha + p * Vs[k][g * 16 + j];
            m = mn;
        }
        __syncthreads();
    }

    const float inv = 1.0f / l;
    float* yo = y + (size_t)(b * TT + q) * DD + h * HD + g * 16;
    #pragma unroll
    for (int j = 0; j < 16; ++j) yo[j] = acc[j] * inv;
}

// ---------------------------------------------------------------------------
extern "C" void kernel_launch(void* const* d_in, const int* in_sizes, int n_in,
                              void* d_out, int out_size, void* d_ws, size_t ws_size,
                              hipStream_t stream)
{
    const float* x     = (const float*)d_in[0];   // [B,T,D]
    const float* Wqkv  = (const float*)d_in[1];   // [D, 3D]
    const float* bqkv  = (const float*)d_in[2];   // [3D]
    const float* Wproj = (const float*)d_in[3];   // [D, D]
    const float* bproj = (const float*)d_in[4];   // [D]
    float* out = (float*)d_out;                   // [B,T,D]

    // Workspace layout: qkv [BT,3D] fp32 (48 MB), y [BT,D] fp32 (16 MB)
    float* qkv = (float*)d_ws;
    float* yb  = qkv + (size_t)BT * QKV_N;

    // 1) QKV projection: [4096,1024] @ [1024,3072] + bias
    {
        dim3 grid(QKV_N / 64, BT / 64);
        gemm_bias_f32<<<grid, 256, 0, stream>>>(x, Wqkv, bqkv, qkv, BT, QKV_N, DD);
    }
    // 2) RoPE in place on q,k
    {
        const int total = BT * 2 * HH * 32;
        rope_inplace<<<total / 256, 256, 0, stream>>>(qkv);
    }
    // 3) Causal flash attention -> y [BT, D]
    {
        dim3 grid(TT / 64, BB * HH);
        attn_causal<<<grid, 256, 0, stream>>>(qkv, yb);
    }
    // 4) Output projection: [4096,1024] @ [1024,1024] + bias
    {
        dim3 grid(DD / 64, BT / 64);
        gemm_bias_f32<<<grid, 256, 0, stream>>>(yb, Wproj, bproj, out, BT, DD, DD);
    }
}

// Round 2
// 623.987 us; speedup vs baseline: 2.5488x; 2.5488x over previous
//
#include <hip/hip_runtime.h>
#include <hip/hip_bf16.h>
#include <cstdint>

// Problem constants
#define BB 2
#define TT 2048
#define DD 1024
#define HH 16
#define HD 64
#define BT (BB*TT)          // 4096
#define QKV_N (3*DD)        // 3072

typedef __attribute__((ext_vector_type(8))) short  short8;   // 8 bf16 = 16B
typedef __attribute__((ext_vector_type(4))) float  f32x4;

static __device__ __forceinline__ ushort f2bf(float f) {
    union { float f; uint32_t u; } v; v.f = f;
    uint32_t u = v.u;
    return (ushort)((u + 0x7FFFu + ((u >> 16) & 1u)) >> 16);   // RNE
}

// ---------------------------------------------------------------------------
// Tiled fp32 GEMM with bias: C[M,N] = A[M,K] @ B[K,N] + bias[N]
// ---------------------------------------------------------------------------
__global__ __launch_bounds__(256) void gemm_bias_f32(
    const float* __restrict__ A, const float* __restrict__ Bm,
    const float* __restrict__ bias, float* __restrict__ C,
    int M, int N, int K)
{
    __shared__ float As[64][17];
    __shared__ float Bs[16][64];

    const int tid = threadIdx.x;
    const int bm = blockIdx.y * 64;
    const int bn = blockIdx.x * 64;
    const int mb = (tid >> 4) << 2;
    const int nb = (tid & 15) << 2;

    float acc[4][4] = {};

    for (int k0 = 0; k0 < K; k0 += 16) {
        {
            const int r  = tid >> 2;
            const int kq = (tid & 3) << 2;
            float4 v = *(const float4*)&A[(size_t)(bm + r) * K + k0 + kq];
            As[r][kq + 0] = v.x; As[r][kq + 1] = v.y;
            As[r][kq + 2] = v.z; As[r][kq + 3] = v.w;
        }
        {
            const int r  = tid >> 4;
            const int nq = (tid & 15) << 2;
            *(float4*)&Bs[r][nq] = *(const float4*)&Bm[(size_t)(k0 + r) * N + bn + nq];
        }
        __syncthreads();

        #pragma unroll
        for (int kk = 0; kk < 16; ++kk) {
            const float a0 = As[mb + 0][kk];
            const float a1 = As[mb + 1][kk];
            const float a2 = As[mb + 2][kk];
            const float a3 = As[mb + 3][kk];
            const float4 b = *(const float4*)&Bs[kk][nb];
            acc[0][0] += a0 * b.x; acc[0][1] += a0 * b.y; acc[0][2] += a0 * b.z; acc[0][3] += a0 * b.w;
            acc[1][0] += a1 * b.x; acc[1][1] += a1 * b.y; acc[1][2] += a1 * b.z; acc[1][3] += a1 * b.w;
            acc[2][0] += a2 * b.x; acc[2][1] += a2 * b.y; acc[2][2] += a2 * b.z; acc[2][3] += a2 * b.w;
            acc[3][0] += a3 * b.x; acc[3][1] += a3 * b.y; acc[3][2] += a3 * b.z; acc[3][3] += a3 * b.w;
        }
        __syncthreads();
    }

    #pragma unroll
    for (int i = 0; i < 4; ++i)
        #pragma unroll
        for (int j = 0; j < 4; ++j)
            C[(size_t)(bm + mb + i) * N + bn + nb + j] = acc[i][j] + bias[bn + nb + j];
}

// ---------------------------------------------------------------------------
// RoPE + bf16 cast + layout conversion.
// In : qkv fp32 [BT, 3D]
// Out: Qb, Kb bf16 [B*H, T, 64] (RoPE'd), Vt bf16 [B*H, 64, T] (transposed)
// Grid: (T/64, B*H), block 256.
// ---------------------------------------------------------------------------
__global__ __launch_bounds__(256) void rope_convert(
    const float* __restrict__ qkv,
    ushort* __restrict__ Qb, ushort* __restrict__ Kb, ushort* __restrict__ Vt)
{
    __shared__ __align__(16) ushort Vs[64][72];

    const int bh = blockIdx.y;
    const int b  = bh >> 4;
    const int h  = bh & 15;
    const int t0 = blockIdx.x * 64;
    const int tid = threadIdx.x;

    // ---- Q and K with RoPE: thread handles row r, pair-base i0 (8 pairs) ----
    {
        const int r  = tid >> 2;
        const int i0 = (tid & 3) * 8;
        const int t  = t0 + r;
        const size_t rowbase = ((size_t)(b * TT + t)) * QKV_N + h * HD;

        float cs[8], sn[8];
        #pragma unroll
        for (int j = 0; j < 8; ++j) {
            const float idx  = (float)(i0 + j);
            const float rate = powf(10000.0f, -idx * (1.0f / 32.0f));
            const float th   = (float)t * rate;
            cs[j] = cosf(th);
            sn[j] = sinf(th);
        }

        #pragma unroll
        for (int w = 0; w < 2; ++w) {
            const float* p = qkv + rowbase + w * DD;
            float4 a0 = *(const float4*)(p + i0);
            float4 a1 = *(const float4*)(p + i0 + 4);
            float4 b0 = *(const float4*)(p + i0 + 32);
            float4 b1 = *(const float4*)(p + i0 + 36);
            float x1[8] = {a0.x, a0.y, a0.z, a0.w, a1.x, a1.y, a1.z, a1.w};
            float x2[8] = {b0.x, b0.y, b0.z, b0.w, b1.x, b1.y, b1.z, b1.w};
            ushort o1[8], o2[8];
            #pragma unroll
            for (int j = 0; j < 8; ++j) {
                o1[j] = f2bf(x1[j] * cs[j] - x2[j] * sn[j]);
                o2[j] = f2bf(x1[j] * sn[j] + x2[j] * cs[j]);
            }
            ushort* outb = (w ? Kb : Qb) + ((size_t)bh * TT + t) * HD;
            *(short8*)(outb + i0)      = *(const short8*)o1;
            *(short8*)(outb + i0 + 32) = *(const short8*)o2;
        }
    }

    // ---- V transpose via LDS ----
    #pragma unroll
    for (int it = 0; it < 4; ++it) {
        const int fi  = tid + it * 256;       // 0..1023
        const int rv  = fi & 63;              // t-row
        const int dv4 = (fi >> 6) * 4;        // dim base
        const float* vp = qkv + ((size_t)(b * TT + t0 + rv)) * QKV_N + 2 * DD + h * HD + dv4;
        float4 v4 = *(const float4*)vp;
        Vs[dv4 + 0][rv] = f2bf(v4.x);
        Vs[dv4 + 1][rv] = f2bf(v4.y);
        Vs[dv4 + 2][rv] = f2bf(v4.z);
        Vs[dv4 + 3][rv] = f2bf(v4.w);
    }
    __syncthreads();
    #pragma unroll
    for (int it = 0; it < 2; ++it) {
        const int fi = tid + it * 256;        // 0..511
        const int d  = fi >> 3;
        const int c8 = (fi & 7) * 8;
        ushort* o = Vt + ((size_t)bh * HD + d) * TT + t0 + c8;
        *(short8*)o = *(const short8*)&Vs[d][c8];
    }
}

// ---------------------------------------------------------------------------
// Causal flash attention, bf16 MFMA (16x16x32).
// Grid: (T/64, B*H), block 256 = 4 waves; each wave owns 16 q-rows.
// Qb/Kb: [B*H, T, 64] bf16 (RoPE'd). Vt: [B*H, 64, T] bf16.
// Out y: [BT, D] fp32, D index = h*64 + d.
// ---------------------------------------------------------------------------
__global__ __launch_bounds__(256) void attn_mfma(
    const ushort* __restrict__ Qb, const ushort* __restrict__ Kb,
    const ushort* __restrict__ Vt, float* __restrict__ y)
{
    __shared__ __align__(16) ushort Ks[64][72];   // [key][dim]
    __shared__ __align__(16) ushort Vs[64][72];   // [dim][key]
    __shared__ __align__(16) ushort Ps[4][16][72];// per-wave [q-local][key]

    const int bh = blockIdx.y;
    const int b  = bh >> 4;
    const int h  = bh & 15;
    const int q0 = blockIdx.x * 64;
    const int tid = threadIdx.x;
    const int w   = tid >> 6;      // wave 0..3
    const int l   = tid & 63;
    const int lr  = l & 15;        // 0..15
    const int lg  = l >> 4;        // 0..3

    // Q fragments (A-operand): row = q0 + w*16 + lr, k = lg*8..+8 (+32)
    const ushort* qrow = Qb + ((size_t)bh * TT + q0 + w * 16 + lr) * HD;
    const short8 qa0 = *(const short8*)(qrow + lg * 8);
    const short8 qa1 = *(const short8*)(qrow + 32 + lg * 8);

    float m_state[4], l_state[4];
    f32x4 acc[4];
    #pragma unroll
    for (int j = 0; j < 4; ++j) {
        m_state[j] = -1e30f; l_state[j] = 0.0f;
        acc[j] = (f32x4){0.f, 0.f, 0.f, 0.f};
    }

    const int nkt = (q0 >> 6) + 1;
    for (int tk = 0; tk < nkt; ++tk) {
        const int k0 = tk << 6;
        // ---- stage K tile [64 keys][64 dims] and Vt tile [64 dims][64 keys] ----
        const ushort* KbBase = Kb + ((size_t)bh * TT + k0) * HD;
        const ushort* VtBase = Vt + ((size_t)bh * HD) * TT + k0;
        #pragma unroll
        for (int it = 0; it < 2; ++it) {
            const int fi = tid + it * 256;    // 0..511
            const int r  = fi >> 3;
            const int c8 = (fi & 7) * 8;
            *(short8*)&Ks[r][c8] = *(const short8*)(KbBase + (size_t)r * HD + c8);
            *(short8*)&Vs[r][c8] = *(const short8*)(VtBase + (size_t)r * TT + c8);
        }
        __syncthreads();

        // ---- QK^T: S[16 q][64 k] per wave ----
        float s[4][4];   // [kn][j]  value S[q-row lg*4+j][key kn*16+lr]
        #pragma unroll
        for (int kn = 0; kn < 4; ++kn) {
            const short8 kf0 = *(const short8*)&Ks[kn * 16 + lr][lg * 8];
            const short8 kf1 = *(const short8*)&Ks[kn * 16 + lr][32 + lg * 8];
            f32x4 t = (f32x4){0.f, 0.f, 0.f, 0.f};
            t = __builtin_amdgcn_mfma_f32_16x16x32_bf16(qa0, kf0, t, 0, 0, 0);
            t = __builtin_amdgcn_mfma_f32_16x16x32_bf16(qa1, kf1, t, 0, 0, 0);
            #pragma unroll
            for (int j = 0; j < 4; ++j) s[kn][j] = t[j] * 0.125f;
        }

        // ---- causal mask on diagonal tile ----
        if (tk == nkt - 1) {
            #pragma unroll
            for (int kn = 0; kn < 4; ++kn)
                #pragma unroll
                for (int j = 0; j < 4; ++j)
                    if (kn * 16 + lr > w * 16 + lg * 4 + j) s[kn][j] = -1e30f;
        }

        // ---- online softmax (per lane: 4 rows; reduce across 16-lane group) ----
        float p[4][4];
        #pragma unroll
        for (int j = 0; j < 4; ++j) {
            float rmax = fmaxf(fmaxf(s[0][j], s[1][j]), fmaxf(s[2][j], s[3][j]));
            #pragma unroll
            for (int off = 1; off < 16; off <<= 1)
                rmax = fmaxf(rmax, __shfl_xor(rmax, off));
            const float newm = fmaxf(m_state[j], rmax);
            const float alpha = __expf(m_state[j] - newm);
            m_state[j] = newm;
            float rsum = 0.0f;
            #pragma unroll
            for (int kn = 0; kn < 4; ++kn) {
                p[kn][j] = __expf(s[kn][j] - newm);
                rsum += p[kn][j];
            }
            #pragma unroll
            for (int off = 1; off < 16; off <<= 1)
                rsum += __shfl_xor(rsum, off);
            l_state[j] = l_state[j] * alpha + rsum;
            #pragma unroll
            for (int dn = 0; dn < 4; ++dn) acc[dn][j] *= alpha;
        }

        // ---- write P to per-wave LDS (bf16) ----
        #pragma unroll
        for (int kn = 0; kn < 4; ++kn)
            #pragma unroll
            for (int j = 0; j < 4; ++j)
                Ps[w][lg * 4 + j][kn * 16 + lr] = f2bf(p[kn][j]);
        __syncthreads();

        // ---- PV: O[16 q][64 d] += P @ V ----
        const short8 pa0 = *(const short8*)&Ps[w][lr][lg * 8];
        const short8 pa1 = *(const short8*)&Ps[w][lr][32 + lg * 8];
        #pragma unroll
        for (int dn = 0; dn < 4; ++dn) {
            const short8 vb0 = *(const short8*)&Vs[dn * 16 + lr][lg * 8];
            const short8 vb1 = *(const short8*)&Vs[dn * 16 + lr][32 + lg * 8];
            acc[dn] = __builtin_amdgcn_mfma_f32_16x16x32_bf16(pa0, vb0, acc[dn], 0, 0, 0);
            acc[dn] = __builtin_amdgcn_mfma_f32_16x16x32_bf16(pa1, vb1, acc[dn], 0, 0, 0);
        }
        __syncthreads();   // protect Ks/Vs/Ps before restage
    }

    // ---- finalize: divide by l, write fp32 y ----
    #pragma unroll
    for (int j = 0; j < 4; ++j) {
        const float inv = 1.0f / l_state[j];
        const int qg = q0 + w * 16 + lg * 4 + j;
        float* yo = y + ((size_t)b * TT + qg) * DD + h * HD;
        #pragma unroll
        for (int dn = 0; dn < 4; ++dn)
            yo[dn * 16 + lr] = acc[dn][j] * inv;
    }
}

// ---------------------------------------------------------------------------
extern "C" void kernel_launch(void* const* d_in, const int* in_sizes, int n_in,
                              void* d_out, int out_size, void* d_ws, size_t ws_size,
                              hipStream_t stream)
{
    const float* x     = (const float*)d_in[0];   // [B,T,D]
    const float* Wqkv  = (const float*)d_in[1];   // [D, 3D]
    const float* bqkv  = (const float*)d_in[2];   // [3D]
    const float* Wproj = (const float*)d_in[3];   // [D, D]
    const float* bproj = (const float*)d_in[4];   // [D]
    float* out = (float*)d_out;                   // [B,T,D]

    // Workspace: qkv fp32 48MB | y fp32 16MB | Qb 8MB | Kb 8MB | Vt 8MB = 88MB
    float*  qkv = (float*)d_ws;
    float*  yb  = qkv + (size_t)BT * QKV_N;          // 12,582,912 floats
    ushort* Qb  = (ushort*)(yb + (size_t)BT * DD);   // 4,194,304 floats
    ushort* Kb  = Qb + (size_t)BB * HH * TT * HD;
    ushort* Vt  = Kb + (size_t)BB * HH * TT * HD;

    // 1) QKV projection (fp32)
    {
        dim3 grid(QKV_N / 64, BT / 64);
        gemm_bias_f32<<<grid, 256, 0, stream>>>(x, Wqkv, bqkv, qkv, BT, QKV_N, DD);
    }
    // 2) RoPE + bf16 + layout (Q/K head-major, V transposed)
    {
        dim3 grid(TT / 64, BB * HH);
        rope_convert<<<grid, 256, 0, stream>>>(qkv, Qb, Kb, Vt);
    }
    // 3) Causal MFMA flash attention -> y [BT, D] fp32
    {
        dim3 grid(TT / 64, BB * HH);
        attn_mfma<<<grid, 256, 0, stream>>>(Qb, Kb, Vt, yb);
    }
    // 4) Output projection (fp32)
    {
        dim3 grid(DD / 64, BT / 64);
        gemm_bias_f32<<<grid, 256, 0, stream>>>(yb, Wproj, bproj, out, BT, DD, DD);
    }
}

// Round 3
// 220.622 us; speedup vs baseline: 7.2087x; 2.8283x over previous
//
#include <hip/hip_runtime.h>
#include <hip/hip_bf16.h>
#include <cstdint>

// Problem constants
#define BB 2
#define TT 2048
#define DD 1024
#define HH 16
#define HD 64
#define BT (BB*TT)          // 4096
#define QKV_N (3*DD)        // 3072

typedef __attribute__((ext_vector_type(8))) short  short8;   // 8 bf16 = 16B
typedef __attribute__((ext_vector_type(4))) short  short4x;  // 4 bf16 = 8B
typedef __attribute__((ext_vector_type(4))) float  f32x4;

static __device__ __forceinline__ ushort f2bf(float f) {
    union { float f; uint32_t u; } v; v.f = f;
    uint32_t u = v.u;
    return (ushort)((u + 0x7FFFu + ((u >> 16) & 1u)) >> 16);   // RNE
}
static __device__ __forceinline__ float bf2f(ushort u) {
    union { uint32_t u; float f; } v; v.u = ((uint32_t)u) << 16; return v.f;
}

typedef const __attribute__((address_space(1))) uint32_t* gp1_t;
typedef __attribute__((address_space(3))) uint32_t* lp3_t;
static __device__ __forceinline__ void gload_lds16(const void* g, void* l) {
    __builtin_amdgcn_global_load_lds((gp1_t)g, (lp3_t)l, 16, 0, 0);
}

// ---------------------------------------------------------------------------
// fp32 -> bf16 cast, 8 elems/thread
// ---------------------------------------------------------------------------
__global__ __launch_bounds__(256) void f32_to_bf16(
    const float* __restrict__ in, ushort* __restrict__ out, int n8)
{
    const int i = blockIdx.x * 256 + threadIdx.x;
    if (i >= n8) return;
    float4 v0 = *(const float4*)(in + (size_t)i * 8);
    float4 v1 = *(const float4*)(in + (size_t)i * 8 + 4);
    ushort o[8] = {f2bf(v0.x), f2bf(v0.y), f2bf(v0.z), f2bf(v0.w),
                   f2bf(v1.x), f2bf(v1.y), f2bf(v1.z), f2bf(v1.w)};
    *(short8*)(out + (size_t)i * 8) = *(const short8*)o;
}

// ---------------------------------------------------------------------------
// W fp32 [K][N] -> Wt bf16 [N][K]  (64x64 tiles via LDS)
// ---------------------------------------------------------------------------
__global__ __launch_bounds__(256) void transpose_w_bf16(
    const float* __restrict__ W, ushort* __restrict__ Wt, int K, int N)
{
    __shared__ ushort Ws[64][72];
    const int n0 = blockIdx.x * 64;
    const int k0 = blockIdx.y * 64;
    const int tid = threadIdx.x;

    #pragma unroll
    for (int it = 0; it < 4; ++it) {
        const int r  = it * 16 + (tid >> 4);
        const int c4 = (tid & 15) * 4;
        float4 v = *(const float4*)&W[(size_t)(k0 + r) * N + n0 + c4];
        Ws[c4 + 0][r] = f2bf(v.x);
        Ws[c4 + 1][r] = f2bf(v.y);
        Ws[c4 + 2][r] = f2bf(v.z);
        Ws[c4 + 3][r] = f2bf(v.w);
    }
    __syncthreads();
    #pragma unroll
    for (int it = 0; it < 2; ++it) {
        const int rn = it * 32 + (tid >> 3);
        const int c8 = (tid & 7) * 8;
        *(short8*)&Wt[(size_t)(n0 + rn) * K + k0 + c8] = *(const short8*)&Ws[rn][c8];
    }
}

// ---------------------------------------------------------------------------
// bf16 MFMA GEMM: C[M][N] = A[M][K] @ Bt[N][K]^T + bias
// 128x128 tile, BK=64, 256 thr = 4 waves (2x2), global_load_lds staging,
// 3-bit XOR chunk swizzle (linear LDS dest + inverse-swizzled global src).
// ---------------------------------------------------------------------------
template<typename OutT>
__global__ __launch_bounds__(256) void gemm_bf16_mfma(
    const ushort* __restrict__ A, const ushort* __restrict__ Bt,
    const float* __restrict__ bias, OutT* __restrict__ C,
    int M, int N, int K)
{
    __shared__ __align__(16) ushort As[128 * 64];
    __shared__ __align__(16) ushort Bs[128 * 64];

    const int tid = threadIdx.x;
    const int w  = tid >> 6, l = tid & 63;
    const int lr = l & 15,  lg = l >> 4;
    const int wm = w >> 1,  wn = w & 1;
    const int m0 = blockIdx.y * 128;
    const int n0 = blockIdx.x * 128;

    f32x4 acc[4][4] = {};

    for (int k0 = 0; k0 < K; k0 += 64) {
        // ---- stage A and B tiles (16 KB each), swizzled source ----
        #pragma unroll
        for (int i = 0; i < 4; ++i) {
            const int f = i * 256 + w * 64 + l;
            const int r = f >> 3, c = f & 7;
            gload_lds16(A + (size_t)(m0 + r) * K + k0 + ((c ^ (r & 7)) << 3),
                        &As[(i * 256 + w * 64) * 8]);
        }
        #pragma unroll
        for (int i = 0; i < 4; ++i) {
            const int f = i * 256 + w * 64 + l;
            const int r = f >> 3, c = f & 7;
            gload_lds16(Bt + (size_t)(n0 + r) * K + k0 + ((c ^ (r & 7)) << 3),
                        &Bs[(i * 256 + w * 64) * 8]);
        }
        __syncthreads();

        // ---- compute: 2 k-halves x 16 MFMA ----
        #pragma unroll
        for (int kk = 0; kk < 2; ++kk) {
            short8 a[4], b[4];
            #pragma unroll
            for (int mi = 0; mi < 4; ++mi) {
                const int row = wm * 64 + mi * 16 + lr;
                const int c   = kk * 4 + lg;
                a[mi] = *(const short8*)&As[row * 64 + ((c ^ (row & 7)) << 3)];
            }
            #pragma unroll
            for (int ni = 0; ni < 4; ++ni) {
                const int row = wn * 64 + ni * 16 + lr;
                const int c   = kk * 4 + lg;
                b[ni] = *(const short8*)&Bs[row * 64 + ((c ^ (row & 7)) << 3)];
            }
            #pragma unroll
            for (int mi = 0; mi < 4; ++mi)
                #pragma unroll
                for (int ni = 0; ni < 4; ++ni)
                    acc[mi][ni] = __builtin_amdgcn_mfma_f32_16x16x32_bf16(
                        a[mi], b[ni], acc[mi][ni], 0, 0, 0);
        }
        __syncthreads();
    }

    // ---- epilogue: bias + store ----
    #pragma unroll
    for (int mi = 0; mi < 4; ++mi) {
        #pragma unroll
        for (int ni = 0; ni < 4; ++ni) {
            const int n = n0 + wn * 64 + ni * 16 + lr;
            const float bv = bias[n];
            #pragma unroll
            for (int j = 0; j < 4; ++j) {
                const int m = m0 + wm * 64 + mi * 16 + lg * 4 + j;
                const float v = acc[mi][ni][j] + bv;
                if constexpr (sizeof(OutT) == 2) C[(size_t)m * N + n] = f2bf(v);
                else                             C[(size_t)m * N + n] = v;
            }
        }
    }
}

// ---------------------------------------------------------------------------
// RoPE + layout conversion (bf16 in, bf16 out).
// In : qkv bf16 [BT, 3D]
// Out: Qb, Kb bf16 [B*H, T, 64] (RoPE'd), Vt bf16 [B*H, 64, T]
// ---------------------------------------------------------------------------
__global__ __launch_bounds__(256) void rope_convert(
    const ushort* __restrict__ qkv,
    ushort* __restrict__ Qb, ushort* __restrict__ Kb, ushort* __restrict__ Vt)
{
    __shared__ __align__(16) ushort Vs[64][72];

    const int bh = blockIdx.y;
    const int b  = bh >> 4;
    const int h  = bh & 15;
    const int t0 = blockIdx.x * 64;
    const int tid = threadIdx.x;

    // ---- Q and K with RoPE ----
    {
        const int r  = tid >> 2;
        const int i0 = (tid & 3) * 8;
        const int t  = t0 + r;
        const size_t rowbase = ((size_t)(b * TT + t)) * QKV_N + h * HD;

        float cs[8], sn[8];
        #pragma unroll
        for (int j = 0; j < 8; ++j) {
            const float idx  = (float)(i0 + j);
            const float rate = powf(10000.0f, -idx * (1.0f / 32.0f));
            const float th   = (float)t * rate;
            cs[j] = cosf(th);
            sn[j] = sinf(th);
        }

        #pragma unroll
        for (int w = 0; w < 2; ++w) {
            const ushort* p = qkv + rowbase + w * DD;
            short8 va = *(const short8*)(p + i0);
            short8 vb = *(const short8*)(p + i0 + 32);
            ushort o1[8], o2[8];
            #pragma unroll
            for (int j = 0; j < 8; ++j) {
                const float x1 = bf2f((ushort)va[j]);
                const float x2 = bf2f((ushort)vb[j]);
                o1[j] = f2bf(x1 * cs[j] - x2 * sn[j]);
                o2[j] = f2bf(x1 * sn[j] + x2 * cs[j]);
            }
            ushort* outb = (w ? Kb : Qb) + ((size_t)bh * TT + t) * HD;
            *(short8*)(outb + i0)      = *(const short8*)o1;
            *(short8*)(outb + i0 + 32) = *(const short8*)o2;
        }
    }

    // ---- V transpose via LDS (no conversion needed, already bf16) ----
    #pragma unroll
    for (int it = 0; it < 4; ++it) {
        const int fi  = tid + it * 256;
        const int rv  = fi & 63;
        const int dv4 = (fi >> 6) * 4;
        const ushort* vp = qkv + ((size_t)(b * TT + t0 + rv)) * QKV_N + 2 * DD + h * HD + dv4;
        short4x v4 = *(const short4x*)vp;
        Vs[dv4 + 0][rv] = (ushort)v4[0];
        Vs[dv4 + 1][rv] = (ushort)v4[1];
        Vs[dv4 + 2][rv] = (ushort)v4[2];
        Vs[dv4 + 3][rv] = (ushort)v4[3];
    }
    __syncthreads();
    #pragma unroll
    for (int it = 0; it < 2; ++it) {
        const int fi = tid + it * 256;
        const int d  = fi >> 3;
        const int c8 = (fi & 7) * 8;
        ushort* o = Vt + ((size_t)bh * HD + d) * TT + t0 + c8;
        *(short8*)o = *(const short8*)&Vs[d][c8];
    }
}

// ---------------------------------------------------------------------------
// Causal flash attention, bf16 MFMA (16x16x32). Writes bf16 y.
// ---------------------------------------------------------------------------
__global__ __launch_bounds__(256) void attn_mfma(
    const ushort* __restrict__ Qb, const ushort* __restrict__ Kb,
    const ushort* __restrict__ Vt, ushort* __restrict__ y)
{
    __shared__ __align__(16) ushort Ks[64][72];   // [key][dim]
    __shared__ __align__(16) ushort Vs[64][72];   // [dim][key]
    __shared__ __align__(16) ushort Ps[4][16][72];// per-wave [q-local][key]

    const int bh = blockIdx.y;
    const int b  = bh >> 4;
    const int h  = bh & 15;
    const int q0 = blockIdx.x * 64;
    const int tid = threadIdx.x;
    const int w   = tid >> 6;
    const int l   = tid & 63;
    const int lr  = l & 15;
    const int lg  = l >> 4;

    const ushort* qrow = Qb + ((size_t)bh * TT + q0 + w * 16 + lr) * HD;
    const short8 qa0 = *(const short8*)(qrow + lg * 8);
    const short8 qa1 = *(const short8*)(qrow + 32 + lg * 8);

    float m_state[4], l_state[4];
    f32x4 acc[4];
    #pragma unroll
    for (int j = 0; j < 4; ++j) {
        m_state[j] = -1e30f; l_state[j] = 0.0f;
        acc[j] = (f32x4){0.f, 0.f, 0.f, 0.f};
    }

    const int nkt = (q0 >> 6) + 1;
    for (int tk = 0; tk < nkt; ++tk) {
        const int k0 = tk << 6;
        const ushort* KbBase = Kb + ((size_t)bh * TT + k0) * HD;
        const ushort* VtBase = Vt + ((size_t)bh * HD) * TT + k0;
        #pragma unroll
        for (int it = 0; it < 2; ++it) {
            const int fi = tid + it * 256;
            const int r  = fi >> 3;
            const int c8 = (fi & 7) * 8;
            *(short8*)&Ks[r][c8] = *(const short8*)(KbBase + (size_t)r * HD + c8);
            *(short8*)&Vs[r][c8] = *(const short8*)(VtBase + (size_t)r * TT + c8);
        }
        __syncthreads();

        float s[4][4];
        #pragma unroll
        for (int kn = 0; kn < 4; ++kn) {
            const short8 kf0 = *(const short8*)&Ks[kn * 16 + lr][lg * 8];
            const short8 kf1 = *(const short8*)&Ks[kn * 16 + lr][32 + lg * 8];
            f32x4 t = (f32x4){0.f, 0.f, 0.f, 0.f};
            t = __builtin_amdgcn_mfma_f32_16x16x32_bf16(qa0, kf0, t, 0, 0, 0);
            t = __builtin_amdgcn_mfma_f32_16x16x32_bf16(qa1, kf1, t, 0, 0, 0);
            #pragma unroll
            for (int j = 0; j < 4; ++j) s[kn][j] = t[j] * 0.125f;
        }

        if (tk == nkt - 1) {
            #pragma unroll
            for (int kn = 0; kn < 4; ++kn)
                #pragma unroll
                for (int j = 0; j < 4; ++j)
                    if (kn * 16 + lr > w * 16 + lg * 4 + j) s[kn][j] = -1e30f;
        }

        float p[4][4];
        #pragma unroll
        for (int j = 0; j < 4; ++j) {
            float rmax = fmaxf(fmaxf(s[0][j], s[1][j]), fmaxf(s[2][j], s[3][j]));
            #pragma unroll
            for (int off = 1; off < 16; off <<= 1)
                rmax = fmaxf(rmax, __shfl_xor(rmax, off));
            const float newm = fmaxf(m_state[j], rmax);
            const float alpha = __expf(m_state[j] - newm);
            m_state[j] = newm;
            float rsum = 0.0f;
            #pragma unroll
            for (int kn = 0; kn < 4; ++kn) {
                p[kn][j] = __expf(s[kn][j] - newm);
                rsum += p[kn][j];
            }
            #pragma unroll
            for (int off = 1; off < 16; off <<= 1)
                rsum += __shfl_xor(rsum, off);
            l_state[j] = l_state[j] * alpha + rsum;
            #pragma unroll
            for (int dn = 0; dn < 4; ++dn) acc[dn][j] *= alpha;
        }

        #pragma unroll
        for (int kn = 0; kn < 4; ++kn)
            #pragma unroll
            for (int j = 0; j < 4; ++j)
                Ps[w][lg * 4 + j][kn * 16 + lr] = f2bf(p[kn][j]);
        __syncthreads();

        const short8 pa0 = *(const short8*)&Ps[w][lr][lg * 8];
        const short8 pa1 = *(const short8*)&Ps[w][lr][32 + lg * 8];
        #pragma unroll
        for (int dn = 0; dn < 4; ++dn) {
            const short8 vb0 = *(const short8*)&Vs[dn * 16 + lr][lg * 8];
            const short8 vb1 = *(const short8*)&Vs[dn * 16 + lr][32 + lg * 8];
            acc[dn] = __builtin_amdgcn_mfma_f32_16x16x32_bf16(pa0, vb0, acc[dn], 0, 0, 0);
            acc[dn] = __builtin_amdgcn_mfma_f32_16x16x32_bf16(pa1, vb1, acc[dn], 0, 0, 0);
        }
        __syncthreads();
    }

    #pragma unroll
    for (int j = 0; j < 4; ++j) {
        const float inv = 1.0f / l_state[j];
        const int qg = q0 + w * 16 + lg * 4 + j;
        ushort* yo = y + ((size_t)b * TT + qg) * DD + h * HD;
        #pragma unroll
        for (int dn = 0; dn < 4; ++dn)
            yo[dn * 16 + lr] = f2bf(acc[dn][j] * inv);
    }
}

// ---------------------------------------------------------------------------
extern "C" void kernel_launch(void* const* d_in, const int* in_sizes, int n_in,
                              void* d_out, int out_size, void* d_ws, size_t ws_size,
                              hipStream_t stream)
{
    const float* x     = (const float*)d_in[0];   // [B,T,D]
    const float* Wqkv  = (const float*)d_in[1];   // [D, 3D]
    const float* bqkv  = (const float*)d_in[2];   // [3D]
    const float* Wproj = (const float*)d_in[3];   // [D, D]
    const float* bproj = (const float*)d_in[4];   // [D]
    float* out = (float*)d_out;                   // [B,T,D]

    // Workspace (all bf16/ushort): qkv 24MB | yb 8 | Qb 8 | Kb 8 | Vt 8 |
    //                              xb 8 | Wqkvt 6 | Wprojt 2  = 72 MB
    ushort* qkv    = (ushort*)d_ws;
    ushort* yb     = qkv    + (size_t)BT * QKV_N;
    ushort* Qb     = yb     + (size_t)BT * DD;
    ushort* Kb     = Qb     + (size_t)BB * HH * TT * HD;
    ushort* Vt     = Kb     + (size_t)BB * HH * TT * HD;
    ushort* xb     = Vt     + (size_t)BB * HH * TT * HD;
    ushort* Wqkvt  = xb     + (size_t)BT * DD;
    ushort* Wprojt = Wqkvt  + (size_t)QKV_N * DD;

    // 0) conversions
    f32_to_bf16<<<(BT * DD / 8 + 255) / 256, 256, 0, stream>>>(x, xb, BT * DD / 8);
    {
        dim3 g1(QKV_N / 64, DD / 64);
        transpose_w_bf16<<<g1, 256, 0, stream>>>(Wqkv, Wqkvt, DD, QKV_N);
        dim3 g2(DD / 64, DD / 64);
        transpose_w_bf16<<<g2, 256, 0, stream>>>(Wproj, Wprojt, DD, DD);
    }
    // 1) QKV projection (bf16 MFMA, bf16 out)
    {
        dim3 grid(QKV_N / 128, BT / 128);
        gemm_bf16_mfma<ushort><<<grid, 256, 0, stream>>>(xb, Wqkvt, bqkv, qkv, BT, QKV_N, DD);
    }
    // 2) RoPE + layout
    {
        dim3 grid(TT / 64, BB * HH);
        rope_convert<<<grid, 256, 0, stream>>>(qkv, Qb, Kb, Vt);
    }
    // 3) Causal MFMA flash attention -> yb bf16
    {
        dim3 grid(TT / 64, BB * HH);
        attn_mfma<<<grid, 256, 0, stream>>>(Qb, Kb, Vt, yb);
    }
    // 4) Output projection (bf16 MFMA, fp32 out)
    {
        dim3 grid(DD / 128, BT / 128);
        gemm_bf16_mfma<float><<<grid, 256, 0, stream>>>(yb, Wprojt, bproj, out, BT, DD, DD);
    }
}

// Round 4
// 170.877 us; speedup vs baseline: 9.3073x; 1.2911x over previous
//
#include <hip/hip_runtime.h>
#include <hip/hip_bf16.h>
#include <cstdint>

// Problem constants
#define BB 2
#define TT 2048
#define DD 1024
#define HH 16
#define HD 64
#define BT (BB*TT)          // 4096
#define QKV_N (3*DD)        // 3072

typedef __attribute__((ext_vector_type(8))) short  short8;   // 8 bf16 = 16B
typedef __attribute__((ext_vector_type(4))) short  short4x;  // 4 bf16 = 8B
typedef __attribute__((ext_vector_type(4))) float  f32x4;
typedef __attribute__((ext_vector_type(16))) float f32x16;

static __device__ __forceinline__ ushort f2bf(float f) {
    union { float f; uint32_t u; } v; v.f = f;
    uint32_t u = v.u;
    return (ushort)((u + 0x7FFFu + ((u >> 16) & 1u)) >> 16);   // RNE
}
static __device__ __forceinline__ float bf2f(ushort u) {
    union { uint32_t u; float f; } v; v.u = ((uint32_t)u) << 16; return v.f;
}

typedef const __attribute__((address_space(1))) uint32_t* gp1_t;
typedef __attribute__((address_space(3))) uint32_t* lp3_t;
static __device__ __forceinline__ void gload_lds16(const void* g, void* l) {
    __builtin_amdgcn_global_load_lds((gp1_t)g, (lp3_t)l, 16, 0, 0);
}

// pack two f32 -> one u32 of 2 bf16 (lo=a, hi=b), single HW instr
static __device__ __forceinline__ uint32_t cvtpk_bf16(float a, float b) {
    uint32_t r;
    asm volatile("v_cvt_pk_bf16_f32 %0, %1, %2" : "=v"(r) : "v"(a), "v"(b));
    return r;
}
// swap hi-half lanes of a with lo-half lanes of b
static __device__ __forceinline__ void pl32swap(uint32_t& a, uint32_t& b) {
    asm volatile("v_permlane32_swap_b32 %0, %1" : "+v"(a), "+v"(b));
}

static __device__ __forceinline__ f32x16 mfma32(short8 a, short8 b, f32x16 c) {
    return __builtin_amdgcn_mfma_f32_32x32x16_bf16(a, b, c, 0, 0, 0);
}

// ---------------------------------------------------------------------------
// fp32 -> bf16 cast, 8 elems/thread
// ---------------------------------------------------------------------------
__global__ __launch_bounds__(256) void f32_to_bf16(
    const float* __restrict__ in, ushort* __restrict__ out, int n8)
{
    const int i = blockIdx.x * 256 + threadIdx.x;
    if (i >= n8) return;
    float4 v0 = *(const float4*)(in + (size_t)i * 8);
    float4 v1 = *(const float4*)(in + (size_t)i * 8 + 4);
    ushort o[8] = {f2bf(v0.x), f2bf(v0.y), f2bf(v0.z), f2bf(v0.w),
                   f2bf(v1.x), f2bf(v1.y), f2bf(v1.z), f2bf(v1.w)};
    *(short8*)(out + (size_t)i * 8) = *(const short8*)o;
}

// ---------------------------------------------------------------------------
// W fp32 [K][N] -> Wt bf16 [N][K]  (64x64 tiles via LDS)
// ---------------------------------------------------------------------------
__global__ __launch_bounds__(256) void transpose_w_bf16(
    const float* __restrict__ W, ushort* __restrict__ Wt, int K, int N)
{
    __shared__ ushort Ws[64][72];
    const int n0 = blockIdx.x * 64;
    const int k0 = blockIdx.y * 64;
    const int tid = threadIdx.x;

    #pragma unroll
    for (int it = 0; it < 4; ++it) {
        const int r  = it * 16 + (tid >> 4);
        const int c4 = (tid & 15) * 4;
        float4 v = *(const float4*)&W[(size_t)(k0 + r) * N + n0 + c4];
        Ws[c4 + 0][r] = f2bf(v.x);
        Ws[c4 + 1][r] = f2bf(v.y);
        Ws[c4 + 2][r] = f2bf(v.z);
        Ws[c4 + 3][r] = f2bf(v.w);
    }
    __syncthreads();
    #pragma unroll
    for (int it = 0; it < 2; ++it) {
        const int rn = it * 32 + (tid >> 3);
        const int c8 = (tid & 7) * 8;
        *(short8*)&Wt[(size_t)(n0 + rn) * K + k0 + c8] = *(const short8*)&Ws[rn][c8];
    }
}

// ---------------------------------------------------------------------------
// bf16 MFMA GEMM: C[M][N] = A[M][K] @ Bt[N][K]^T + bias   (m97 structure)
// ---------------------------------------------------------------------------
template<typename OutT>
__global__ __launch_bounds__(256) void gemm_bf16_mfma(
    const ushort* __restrict__ A, const ushort* __restrict__ Bt,
    const float* __restrict__ bias, OutT* __restrict__ C,
    int M, int N, int K)
{
    __shared__ __align__(16) ushort As[128 * 64];
    __shared__ __align__(16) ushort Bs[128 * 64];

    const int tid = threadIdx.x;
    const int w  = tid >> 6, l = tid & 63;
    const int lr = l & 15,  lg = l >> 4;
    const int wm = w >> 1,  wn = w & 1;
    const int m0 = blockIdx.y * 128;
    const int n0 = blockIdx.x * 128;

    f32x4 acc[4][4] = {};

    for (int k0 = 0; k0 < K; k0 += 64) {
        #pragma unroll
        for (int i = 0; i < 4; ++i) {
            const int f = i * 256 + w * 64 + l;
            const int r = f >> 3, c = f & 7;
            gload_lds16(A + (size_t)(m0 + r) * K + k0 + ((c ^ (r & 7)) << 3),
                        &As[(i * 256 + w * 64) * 8]);
        }
        #pragma unroll
        for (int i = 0; i < 4; ++i) {
            const int f = i * 256 + w * 64 + l;
            const int r = f >> 3, c = f & 7;
            gload_lds16(Bt + (size_t)(n0 + r) * K + k0 + ((c ^ (r & 7)) << 3),
                        &Bs[(i * 256 + w * 64) * 8]);
        }
        __syncthreads();

        #pragma unroll
        for (int kk = 0; kk < 2; ++kk) {
            short8 a[4], b[4];
            #pragma unroll
            for (int mi = 0; mi < 4; ++mi) {
                const int row = wm * 64 + mi * 16 + lr;
                const int c   = kk * 4 + lg;
                a[mi] = *(const short8*)&As[row * 64 + ((c ^ (row & 7)) << 3)];
            }
            #pragma unroll
            for (int ni = 0; ni < 4; ++ni) {
                const int row = wn * 64 + ni * 16 + lr;
                const int c   = kk * 4 + lg;
                b[ni] = *(const short8*)&Bs[row * 64 + ((c ^ (row & 7)) << 3)];
            }
            #pragma unroll
            for (int mi = 0; mi < 4; ++mi)
                #pragma unroll
                for (int ni = 0; ni < 4; ++ni)
                    acc[mi][ni] = __builtin_amdgcn_mfma_f32_16x16x32_bf16(
                        a[mi], b[ni], acc[mi][ni], 0, 0, 0);
        }
        __syncthreads();
    }

    #pragma unroll
    for (int mi = 0; mi < 4; ++mi) {
        #pragma unroll
        for (int ni = 0; ni < 4; ++ni) {
            const int n = n0 + wn * 64 + ni * 16 + lr;
            const float bv = bias[n];
            #pragma unroll
            for (int j = 0; j < 4; ++j) {
                const int m = m0 + wm * 64 + mi * 16 + lg * 4 + j;
                const float v = acc[mi][ni][j] + bv;
                if constexpr (sizeof(OutT) == 2) C[(size_t)m * N + n] = f2bf(v);
                else                             C[(size_t)m * N + n] = v;
            }
        }
    }
}

// ---------------------------------------------------------------------------
// RoPE + layout conversion (bf16 in, bf16 out). Q pre-scaled by 1/8 (exact).
// Out: Qb, Kb bf16 [B*H, T, 64] (RoPE'd), Vt bf16 [B*H, 64, T]
// ---------------------------------------------------------------------------
__global__ __launch_bounds__(256) void rope_convert(
    const ushort* __restrict__ qkv,
    ushort* __restrict__ Qb, ushort* __restrict__ Kb, ushort* __restrict__ Vt)
{
    __shared__ __align__(16) ushort Vs[64][72];

    const int bh = blockIdx.y;
    const int b  = bh >> 4;
    const int h  = bh & 15;
    const int t0 = blockIdx.x * 64;
    const int tid = threadIdx.x;

    {
        const int r  = tid >> 2;
        const int i0 = (tid & 3) * 8;
        const int t  = t0 + r;
        const size_t rowbase = ((size_t)(b * TT + t)) * QKV_N + h * HD;

        float cs[8], sn[8];
        #pragma unroll
        for (int j = 0; j < 8; ++j) {
            const float idx  = (float)(i0 + j);
            const float rate = powf(10000.0f, -idx * (1.0f / 32.0f));
            const float th   = (float)t * rate;
            cs[j] = cosf(th);
            sn[j] = sinf(th);
        }

        #pragma unroll
        for (int w = 0; w < 2; ++w) {
            const float sc = w ? 1.0f : 0.125f;   // fold 1/sqrt(64) into Q
            const ushort* p = qkv + rowbase + w * DD;
            short8 va = *(const short8*)(p + i0);
            short8 vb = *(const short8*)(p + i0 + 32);
            ushort o1[8], o2[8];
            #pragma unroll
            for (int j = 0; j < 8; ++j) {
                const float x1 = bf2f((ushort)va[j]);
                const float x2 = bf2f((ushort)vb[j]);
                o1[j] = f2bf((x1 * cs[j] - x2 * sn[j]) * sc);
                o2[j] = f2bf((x1 * sn[j] + x2 * cs[j]) * sc);
            }
            ushort* outb = (w ? Kb : Qb) + ((size_t)bh * TT + t) * HD;
            *(short8*)(outb + i0)      = *(const short8*)o1;
            *(short8*)(outb + i0 + 32) = *(const short8*)o2;
        }
    }

    #pragma unroll
    for (int it = 0; it < 4; ++it) {
        const int fi  = tid + it * 256;
        const int rv  = fi & 63;
        const int dv4 = (fi >> 6) * 4;
        const ushort* vp = qkv + ((size_t)(b * TT + t0 + rv)) * QKV_N + 2 * DD + h * HD + dv4;
        short4x v4 = *(const short4x*)vp;
        Vs[dv4 + 0][rv] = (ushort)v4[0];
        Vs[dv4 + 1][rv] = (ushort)v4[1];
        Vs[dv4 + 2][rv] = (ushort)v4[2];
        Vs[dv4 + 3][rv] = (ushort)v4[3];
    }
    __syncthreads();
    #pragma unroll
    for (int it = 0; it < 2; ++it) {
        const int fi = tid + it * 256;
        const int d  = fi >> 3;
        const int c8 = (fi & 7) * 8;
        ushort* o = Vt + ((size_t)bh * HD + d) * TT + t0 + c8;
        *(short8*)o = *(const short8*)&Vs[d][c8];
    }
}

// ---------------------------------------------------------------------------
// Causal flash attention, 32x32x16 MFMA, swapped QK^T, in-register softmax.
// Block = 256 thr = 4 waves; wave owns 32 q-rows; block = 128 q-rows.
// Grid (16, B*H); qb = 15 - blockIdx.x (heavy blocks first).
// KV tile = 64 keys, double-buffered LDS, global_load_lds staging w/ XOR swizzle.
// ---------------------------------------------------------------------------
__global__ __launch_bounds__(256, 2) void attn_mfma32(
    const ushort* __restrict__ Qb, const ushort* __restrict__ Kb,
    const ushort* __restrict__ Vt, ushort* __restrict__ y)
{
    __shared__ __align__(16) ushort Ksm[2][64 * 64];   // [key][d], chunk-swizzled
    __shared__ __align__(16) ushort Vsm[2][64 * 64];   // [d][key], chunk-swizzled

    const int bh = blockIdx.y;
    const int b  = bh >> 4;
    const int h  = bh & 15;
    const int qb = 15 - (int)blockIdx.x;
    const int q0b = qb * 128;
    const int tid = threadIdx.x;
    const int w   = tid >> 6;
    const int l   = tid & 63;
    const int lq  = l & 31;       // q-col / d-row / k-row index
    const int hi  = l >> 5;
    const int wq0 = q0b + w * 32;
    const int qg  = wq0 + lq;     // this lane's q (softmax state owner)

    // Q fragments (B-operand), 4 d-chunks of 16
    short8 qf[4];
    {
        const ushort* qrow = Qb + ((size_t)bh * TT + wq0 + lq) * HD + hi * 8;
        #pragma unroll
        for (int dc = 0; dc < 4; ++dc)
            qf[dc] = *(const short8*)(qrow + dc * 16);
    }

    f32x16 acc0 = {}, acc1 = {};     // O[q-rows][d 0-31], [d 32-63]
    float m = -1e30f, lsum = 0.0f;

    const int nt = 2 * qb + 2;       // 64-key tiles

    // ---- prologue: stage tile 0 into buf 0 ----
    #pragma unroll
    for (int i = 0; i < 2; ++i) {
        const int f = i * 256 + w * 64 + l;
        const int r = f >> 3, c = f & 7;
        const int sw = (c ^ (r & 7)) << 3;
        gload_lds16(Kb + ((size_t)bh * TT + r) * HD + sw,
                    &Ksm[0][(i * 256 + w * 64) * 8]);
        gload_lds16(Vt + ((size_t)bh * HD + r) * TT + sw,
                    &Vsm[0][(i * 256 + w * 64) * 8]);
    }
    __syncthreads();

    for (int t = 0; t < nt; ++t) {
        const int cur = t & 1;
        const int k0  = t * 64;

        // ---- prefetch next tile into other buffer ----
        if (t + 1 < nt) {
            const int nk0 = k0 + 64;
            #pragma unroll
            for (int i = 0; i < 2; ++i) {
                const int f = i * 256 + w * 64 + l;
                const int r = f >> 3, c = f & 7;
                const int sw = (c ^ (r & 7)) << 3;
                gload_lds16(Kb + ((size_t)bh * TT + nk0 + r) * HD + sw,
                            &Ksm[cur ^ 1][(i * 256 + w * 64) * 8]);
                gload_lds16(Vt + ((size_t)bh * HD + r) * TT + nk0 + sw,
                            &Vsm[cur ^ 1][(i * 256 + w * 64) * 8]);
            }
        }

        if (k0 <= wq0 + 31) {   // wave-uniform: tile not fully masked
            const bool needmask = (k0 + 63) > wq0;

            // ---- S^T = K @ Q^T : lane holds 32 keys for q = qg ----
            f32x16 st0 = {}, st1 = {};
            #pragma unroll
            for (int dc = 0; dc < 4; ++dc) {
                const int c  = dc * 2 + hi;
                const int r0 = lq;
                const int r1 = 32 + lq;
                const short8 kf0 = *(const short8*)&Ksm[cur][r0 * 64 + ((c ^ (r0 & 7)) << 3)];
                const short8 kf1 = *(const short8*)&Ksm[cur][r1 * 64 + ((c ^ (r1 & 7)) << 3)];
                st0 = mfma32(kf0, qf[dc], st0);
                st1 = mfma32(kf1, qf[dc], st1);
            }

            // ---- mask + row max (16 local + 1 shfl) ----
            float pm = -1e30f;
            #pragma unroll
            for (int r = 0; r < 16; ++r) {
                float v0 = st0[r], v1 = st1[r];
                if (needmask) {
                    const int kk = k0 + (r & 3) + 8 * (r >> 2) + 4 * hi;
                    if (kk > qg)      v0 = -1e30f;
                    if (kk + 32 > qg) v1 = -1e30f;
                }
                st0[r] = v0; st1[r] = v1;
                pm = fmaxf(pm, fmaxf(v0, v1));
            }
            pm = fmaxf(pm, __shfl_xor(pm, 32));
            const float nm    = fmaxf(m, pm);
            const float alpha = __expf(m - nm);
            m = nm;

            // ---- exp + row sum ----
            float rs = 0.0f;
            #pragma unroll
            for (int r = 0; r < 16; ++r) {
                const float p0 = __expf(st0[r] - nm);
                const float p1 = __expf(st1[r] - nm);
                st0[r] = p0; st1[r] = p1;
                rs += p0 + p1;
            }
            rs += __shfl_xor(rs, 32);
            lsum = lsum * alpha + rs;

            // ---- rescale O by per-row alpha (broadcast from softmax lanes) ----
            #pragma unroll
            for (int r = 0; r < 16; ++r) {
                const float ar = __shfl(alpha, (r & 3) + 8 * (r >> 2) + 4 * hi);
                acc0[r] *= ar; acc1[r] *= ar;
            }

            // ---- pack P -> bf16 A-fragments via cvt_pk + permlane32_swap ----
            short8 pfr[4];
            #pragma unroll
            for (int sub = 0; sub < 2; ++sub) {
                const f32x16& ps = sub ? st1 : st0;
                uint32_t A0 = cvtpk_bf16(ps[0],  ps[1]);
                uint32_t A1 = cvtpk_bf16(ps[2],  ps[3]);
                uint32_t B0 = cvtpk_bf16(ps[4],  ps[5]);
                uint32_t B1 = cvtpk_bf16(ps[6],  ps[7]);
                uint32_t C0 = cvtpk_bf16(ps[8],  ps[9]);
                uint32_t C1 = cvtpk_bf16(ps[10], ps[11]);
                uint32_t D0 = cvtpk_bf16(ps[12], ps[13]);
                uint32_t D1 = cvtpk_bf16(ps[14], ps[15]);
                pl32swap(A0, B0); pl32swap(A1, B1);
                pl32swap(C0, D0); pl32swap(C1, D1);
                union { uint32_t u[4]; short8 s; } f0, f1;
                f0.u[0] = A0; f0.u[1] = A1; f0.u[2] = B0; f0.u[3] = B1;
                f1.u[0] = C0; f1.u[1] = C1; f1.u[2] = D0; f1.u[3] = D1;
                pfr[sub * 2]     = f0.s;
                pfr[sub * 2 + 1] = f1.s;
            }

            // ---- PV: O += P @ V ----
            #pragma unroll
            for (int kc = 0; kc < 4; ++kc) {
                const int c  = kc * 2 + hi;
                const int r0 = lq;
                const int r1 = 32 + lq;
                const short8 vf0 = *(const short8*)&Vsm[cur][r0 * 64 + ((c ^ (r0 & 7)) << 3)];
                const short8 vf1 = *(const short8*)&Vsm[cur][r1 * 64 + ((c ^ (r1 & 7)) << 3)];
                acc0 = mfma32(pfr[kc], vf0, acc0);
                acc1 = mfma32(pfr[kc], vf1, acc1);
            }
        }
        __syncthreads();   // next-tile staging complete + everyone done with cur
    }

    // ---- epilogue: divide by l (broadcast per row), write bf16 y ----
    const float inv = 1.0f / lsum;
    #pragma unroll
    for (int r = 0; r < 16; ++r) {
        const int row = (r & 3) + 8 * (r >> 2) + 4 * hi;
        const float ir = __shfl(inv, row);
        ushort* yo = y + ((size_t)b * TT + q0b + w * 32 + row) * DD + h * HD;
        yo[lq]      = f2bf(acc0[r] * ir);
        yo[32 + lq] = f2bf(acc1[r] * ir);
    }
}

// ---------------------------------------------------------------------------
extern "C" void kernel_launch(void* const* d_in, const int* in_sizes, int n_in,
                              void* d_out, int out_size, void* d_ws, size_t ws_size,
                              hipStream_t stream)
{
    const float* x     = (const float*)d_in[0];   // [B,T,D]
    const float* Wqkv  = (const float*)d_in[1];   // [D, 3D]
    const float* bqkv  = (const float*)d_in[2];   // [3D]
    const float* Wproj = (const float*)d_in[3];   // [D, D]
    const float* bproj = (const float*)d_in[4];   // [D]
    float* out = (float*)d_out;                   // [B,T,D]

    ushort* qkv    = (ushort*)d_ws;
    ushort* yb     = qkv    + (size_t)BT * QKV_N;
    ushort* Qb     = yb     + (size_t)BT * DD;
    ushort* Kb     = Qb     + (size_t)BB * HH * TT * HD;
    ushort* Vt     = Kb     + (size_t)BB * HH * TT * HD;
    ushort* xb     = Vt     + (size_t)BB * HH * TT * HD;
    ushort* Wqkvt  = xb     + (size_t)BT * DD;
    ushort* Wprojt = Wqkvt  + (size_t)QKV_N * DD;

    // 0) conversions
    f32_to_bf16<<<(BT * DD / 8 + 255) / 256, 256, 0, stream>>>(x, xb, BT * DD / 8);
    {
        dim3 g1(QKV_N / 64, DD / 64);
        transpose_w_bf16<<<g1, 256, 0, stream>>>(Wqkv, Wqkvt, DD, QKV_N);
        dim3 g2(DD / 64, DD / 64);
        transpose_w_bf16<<<g2, 256, 0, stream>>>(Wproj, Wprojt, DD, DD);
    }
    // 1) QKV projection (bf16 MFMA, bf16 out)
    {
        dim3 grid(QKV_N / 128, BT / 128);
        gemm_bf16_mfma<ushort><<<grid, 256, 0, stream>>>(xb, Wqkvt, bqkv, qkv, BT, QKV_N, DD);
    }
    // 2) RoPE + layout (Q pre-scaled by 1/8)
    {
        dim3 grid(TT / 64, BB * HH);
        rope_convert<<<grid, 256, 0, stream>>>(qkv, Qb, Kb, Vt);
    }
    // 3) Causal MFMA flash attention (32x32, swapped QK^T) -> yb bf16
    {
        dim3 grid(16, BB * HH);
        attn_mfma32<<<grid, 256, 0, stream>>>(Qb, Kb, Vt, yb);
    }
    // 4) Output projection (bf16 MFMA, fp32 out)
    {
        dim3 grid(DD / 128, BT / 128);
        gemm_bf16_mfma<float><<<grid, 256, 0, stream>>>(yb, Wprojt, bproj, out, BT, DD, DD);
    }
}

// Round 5
// 166.610 us; speedup vs baseline: 9.5456x; 1.0256x over previous
//
#include <hip/hip_runtime.h>
#include <hip/hip_bf16.h>
#include <cstdint>

// Problem constants
#define BB 2
#define TT 2048
#define DD 1024
#define HH 16
#define HD 64
#define BT (BB*TT)          // 4096
#define QKV_N (3*DD)        // 3072

typedef __attribute__((ext_vector_type(8))) short  short8;   // 8 bf16 = 16B
typedef __attribute__((ext_vector_type(4))) short  short4x;  // 4 bf16 = 8B
typedef __attribute__((ext_vector_type(4))) float  f32x4;
typedef __attribute__((ext_vector_type(16))) float f32x16;

static __device__ __forceinline__ ushort f2bf(float f) {
    union { float f; uint32_t u; } v; v.f = f;
    uint32_t u = v.u;
    return (ushort)((u + 0x7FFFu + ((u >> 16) & 1u)) >> 16);   // RNE
}
static __device__ __forceinline__ float bf2f(ushort u) {
    union { uint32_t u; float f; } v; v.u = ((uint32_t)u) << 16; return v.f;
}

typedef const __attribute__((address_space(1))) uint32_t* gp1_t;
typedef __attribute__((address_space(3))) uint32_t* lp3_t;
static __device__ __forceinline__ void gload_lds16(const void* g, void* l) {
    __builtin_amdgcn_global_load_lds((gp1_t)g, (lp3_t)l, 16, 0, 0);
}

// pack two f32 -> one u32 of 2 bf16 (lo=a, hi=b), single HW instr
static __device__ __forceinline__ uint32_t cvtpk_bf16(float a, float b) {
    uint32_t r;
    asm volatile("v_cvt_pk_bf16_f32 %0, %1, %2" : "=v"(r) : "v"(a), "v"(b));
    return r;
}
// swap hi-half lanes of a with lo-half lanes of b
static __device__ __forceinline__ void pl32swap(uint32_t& a, uint32_t& b) {
    asm volatile("v_permlane32_swap_b32 %0, %1" : "+v"(a), "+v"(b));
}

static __device__ __forceinline__ f32x16 mfma32(short8 a, short8 b, f32x16 c) {
    return __builtin_amdgcn_mfma_f32_32x32x16_bf16(a, b, c, 0, 0, 0);
}

// ---------------------------------------------------------------------------
// fp32 -> bf16 cast, 8 elems/thread
// ---------------------------------------------------------------------------
__global__ __launch_bounds__(256) void f32_to_bf16(
    const float* __restrict__ in, ushort* __restrict__ out, int n8)
{
    const int i = blockIdx.x * 256 + threadIdx.x;
    if (i >= n8) return;
    float4 v0 = *(const float4*)(in + (size_t)i * 8);
    float4 v1 = *(const float4*)(in + (size_t)i * 8 + 4);
    ushort o[8] = {f2bf(v0.x), f2bf(v0.y), f2bf(v0.z), f2bf(v0.w),
                   f2bf(v1.x), f2bf(v1.y), f2bf(v1.z), f2bf(v1.w)};
    *(short8*)(out + (size_t)i * 8) = *(const short8*)o;
}

// ---------------------------------------------------------------------------
// W fp32 [K][N] -> Wt bf16 [N][K]  (64x64 tiles via LDS)
// ---------------------------------------------------------------------------
__global__ __launch_bounds__(256) void transpose_w_bf16(
    const float* __restrict__ W, ushort* __restrict__ Wt, int K, int N)
{
    __shared__ ushort Ws[64][72];
    const int n0 = blockIdx.x * 64;
    const int k0 = blockIdx.y * 64;
    const int tid = threadIdx.x;

    #pragma unroll
    for (int it = 0; it < 4; ++it) {
        const int r  = it * 16 + (tid >> 4);
        const int c4 = (tid & 15) * 4;
        float4 v = *(const float4*)&W[(size_t)(k0 + r) * N + n0 + c4];
        Ws[c4 + 0][r] = f2bf(v.x);
        Ws[c4 + 1][r] = f2bf(v.y);
        Ws[c4 + 2][r] = f2bf(v.z);
        Ws[c4 + 3][r] = f2bf(v.w);
    }
    __syncthreads();
    #pragma unroll
    for (int it = 0; it < 2; ++it) {
        const int rn = it * 32 + (tid >> 3);
        const int c8 = (tid & 7) * 8;
        *(short8*)&Wt[(size_t)(n0 + rn) * K + k0 + c8] = *(const short8*)&Ws[rn][c8];
    }
}

// ---------------------------------------------------------------------------
// bf16 MFMA GEMM: C[M][N] = A[M][K] @ Bt[N][K]^T + bias   (m97 structure)
// ---------------------------------------------------------------------------
template<typename OutT>
__global__ __launch_bounds__(256) void gemm_bf16_mfma(
    const ushort* __restrict__ A, const ushort* __restrict__ Bt,
    const float* __restrict__ bias, OutT* __restrict__ C,
    int M, int N, int K)
{
    __shared__ __align__(16) ushort As[128 * 64];
    __shared__ __align__(16) ushort Bs[128 * 64];

    const int tid = threadIdx.x;
    const int w  = tid >> 6, l = tid & 63;
    const int lr = l & 15,  lg = l >> 4;
    const int wm = w >> 1,  wn = w & 1;
    const int m0 = blockIdx.y * 128;
    const int n0 = blockIdx.x * 128;

    f32x4 acc[4][4] = {};

    for (int k0 = 0; k0 < K; k0 += 64) {
        #pragma unroll
        for (int i = 0; i < 4; ++i) {
            const int f = i * 256 + w * 64 + l;
            const int r = f >> 3, c = f & 7;
            gload_lds16(A + (size_t)(m0 + r) * K + k0 + ((c ^ (r & 7)) << 3),
                        &As[(i * 256 + w * 64) * 8]);
        }
        #pragma unroll
        for (int i = 0; i < 4; ++i) {
            const int f = i * 256 + w * 64 + l;
            const int r = f >> 3, c = f & 7;
            gload_lds16(Bt + (size_t)(n0 + r) * K + k0 + ((c ^ (r & 7)) << 3),
                        &Bs[(i * 256 + w * 64) * 8]);
        }
        __syncthreads();

        #pragma unroll
        for (int kk = 0; kk < 2; ++kk) {
            short8 a[4], b[4];
            #pragma unroll
            for (int mi = 0; mi < 4; ++mi) {
                const int row = wm * 64 + mi * 16 + lr;
                const int c   = kk * 4 + lg;
                a[mi] = *(const short8*)&As[row * 64 + ((c ^ (row & 7)) << 3)];
            }
            #pragma unroll
            for (int ni = 0; ni < 4; ++ni) {
                const int row = wn * 64 + ni * 16 + lr;
                const int c   = kk * 4 + lg;
                b[ni] = *(const short8*)&Bs[row * 64 + ((c ^ (row & 7)) << 3)];
            }
            #pragma unroll
            for (int mi = 0; mi < 4; ++mi)
                #pragma unroll
                for (int ni = 0; ni < 4; ++ni)
                    acc[mi][ni] = __builtin_amdgcn_mfma_f32_16x16x32_bf16(
                        a[mi], b[ni], acc[mi][ni], 0, 0, 0);
        }
        __syncthreads();
    }

    #pragma unroll
    for (int mi = 0; mi < 4; ++mi) {
        #pragma unroll
        for (int ni = 0; ni < 4; ++ni) {
            const int n = n0 + wn * 64 + ni * 16 + lr;
            const float bv = bias[n];
            #pragma unroll
            for (int j = 0; j < 4; ++j) {
                const int m = m0 + wm * 64 + mi * 16 + lg * 4 + j;
                const float v = acc[mi][ni][j] + bv;
                if constexpr (sizeof(OutT) == 2) C[(size_t)m * N + n] = f2bf(v);
                else                             C[(size_t)m * N + n] = v;
            }
        }
    }
}

// ---------------------------------------------------------------------------
// RoPE + layout conversion (bf16 in, bf16 out). Q pre-scaled by 1/8 (exact).
// Out: Qb, Kb bf16 [B*H, T, 64] (RoPE'd), Vt bf16 [B*H, 64, T]
// ---------------------------------------------------------------------------
__global__ __launch_bounds__(256) void rope_convert(
    const ushort* __restrict__ qkv,
    ushort* __restrict__ Qb, ushort* __restrict__ Kb, ushort* __restrict__ Vt)
{
    __shared__ __align__(16) ushort Vs[64][72];

    const int bh = blockIdx.y;
    const int b  = bh >> 4;
    const int h  = bh & 15;
    const int t0 = blockIdx.x * 64;
    const int tid = threadIdx.x;

    {
        const int r  = tid >> 2;
        const int i0 = (tid & 3) * 8;
        const int t  = t0 + r;
        const size_t rowbase = ((size_t)(b * TT + t)) * QKV_N + h * HD;

        float cs[8], sn[8];
        #pragma unroll
        for (int j = 0; j < 8; ++j) {
            const float idx  = (float)(i0 + j);
            const float rate = powf(10000.0f, -idx * (1.0f / 32.0f));
            const float th   = (float)t * rate;
            cs[j] = cosf(th);
            sn[j] = sinf(th);
        }

        #pragma unroll
        for (int w = 0; w < 2; ++w) {
            const float sc = w ? 1.0f : 0.125f;   // fold 1/sqrt(64) into Q
            const ushort* p = qkv + rowbase + w * DD;
            short8 va = *(const short8*)(p + i0);
            short8 vb = *(const short8*)(p + i0 + 32);
            ushort o1[8], o2[8];
            #pragma unroll
            for (int j = 0; j < 8; ++j) {
                const float x1 = bf2f((ushort)va[j]);
                const float x2 = bf2f((ushort)vb[j]);
                o1[j] = f2bf((x1 * cs[j] - x2 * sn[j]) * sc);
                o2[j] = f2bf((x1 * sn[j] + x2 * cs[j]) * sc);
            }
            ushort* outb = (w ? Kb : Qb) + ((size_t)bh * TT + t) * HD;
            *(short8*)(outb + i0)      = *(const short8*)o1;
            *(short8*)(outb + i0 + 32) = *(const short8*)o2;
        }
    }

    #pragma unroll
    for (int it = 0; it < 4; ++it) {
        const int fi  = tid + it * 256;
        const int rv  = fi & 63;
        const int dv4 = (fi >> 6) * 4;
        const ushort* vp = qkv + ((size_t)(b * TT + t0 + rv)) * QKV_N + 2 * DD + h * HD + dv4;
        short4x v4 = *(const short4x*)vp;
        Vs[dv4 + 0][rv] = (ushort)v4[0];
        Vs[dv4 + 1][rv] = (ushort)v4[1];
        Vs[dv4 + 2][rv] = (ushort)v4[2];
        Vs[dv4 + 3][rv] = (ushort)v4[3];
    }
    __syncthreads();
    #pragma unroll
    for (int it = 0; it < 2; ++it) {
        const int fi = tid + it * 256;
        const int d  = fi >> 3;
        const int c8 = (fi & 7) * 8;
        ushort* o = Vt + ((size_t)bh * HD + d) * TT + t0 + c8;
        *(short8*)o = *(const short8*)&Vs[d][c8];
    }
}

// ---------------------------------------------------------------------------
// Causal flash attention, 32x32x16 MFMA, swapped QK^T, in-register softmax,
// NO LDS: each wave independently owns 32 q-rows, reads K/V from global (L2).
// Block = 4 independent waves, all same head; q-tiles paired {2j,2j+1,63-2j-1,
// 63-2j} so per-block work is constant. Defer-max (THR=8) skips most rescales.
// Grid: 512 blocks (bid&31 = head, bid>>5 = j); heavy q-tiles dispatch first.
// ---------------------------------------------------------------------------
__global__ __launch_bounds__(256) void attn_wave32(
    const ushort* __restrict__ Qb, const ushort* __restrict__ Kb,
    const ushort* __restrict__ Vt, ushort* __restrict__ y)
{
    const int bid = blockIdx.x;
    const int bh  = bid & 31;
    const int j   = bid >> 5;
    const int b   = bh >> 4;
    const int h   = bh & 15;
    const int tid = threadIdx.x;
    const int w   = tid >> 6;
    const int l   = tid & 63;
    const int lq  = l & 31;
    const int hi  = l >> 5;

    const int qt  = (w < 2) ? (j * 2 + w) : (63 - (j * 2 + (w - 2)));
    const int wq0 = qt * 32;
    const int qg  = wq0 + lq;     // this lane's q (softmax state owner)

    const ushort* Kbh = Kb + (size_t)bh * TT * HD;
    const ushort* Vbh = Vt + (size_t)bh * HD * TT;

    // Q fragments (B-operand), 4 d-chunks of 16
    short8 qf[4];
    {
        const ushort* qrow = Qb + ((size_t)bh * TT + wq0 + lq) * HD + hi * 8;
        #pragma unroll
        for (int dc = 0; dc < 4; ++dc)
            qf[dc] = *(const short8*)(qrow + dc * 16);
    }

    f32x16 acc0 = {}, acc1 = {};     // O[q-rows][d 0-31], [d 32-63]
    float m = -1e30f, lsum = 0.0f;

    const int nt = (wq0 >> 6) + 1;   // 64-key tiles

    for (int t = 0; t < nt; ++t) {
        const int k0 = t * 64;

        // ---- K fragments straight from global (A-operand: 32 keys x 16 d) ----
        short8 kf0[4], kf1[4];
        #pragma unroll
        for (int dc = 0; dc < 4; ++dc) {
            const int co = (dc * 2 + hi) * 8;
            kf0[dc] = *(const short8*)(Kbh + (size_t)(k0 + lq) * HD + co);
            kf1[dc] = *(const short8*)(Kbh + (size_t)(k0 + 32 + lq) * HD + co);
        }
        // ---- V fragments (B-operand: 32 d x 16 keys) ----
        short8 vf0[4], vf1[4];
        #pragma unroll
        for (int kc = 0; kc < 4; ++kc) {
            const int co = k0 + (kc * 2 + hi) * 8;
            vf0[kc] = *(const short8*)(Vbh + (size_t)lq * TT + co);
            vf1[kc] = *(const short8*)(Vbh + (size_t)(32 + lq) * TT + co);
        }

        // ---- S^T = K @ Q^T : lane holds 32 keys for q = qg ----
        f32x16 st0 = {}, st1 = {};
        #pragma unroll
        for (int dc = 0; dc < 4; ++dc) {
            st0 = mfma32(kf0[dc], qf[dc], st0);
            st1 = mfma32(kf1[dc], qf[dc], st1);
        }

        // ---- mask + row max ----
        const bool needmask = (t == nt - 1);
        float pm = -1e30f;
        #pragma unroll
        for (int r = 0; r < 16; ++r) {
            float v0 = st0[r], v1 = st1[r];
            if (needmask) {
                const int kk = k0 + (r & 3) + 8 * (r >> 2) + 4 * hi;
                if (kk > qg)      v0 = -1e30f;
                if (kk + 32 > qg) v1 = -1e30f;
            }
            st0[r] = v0; st1[r] = v1;
            pm = fmaxf(pm, fmaxf(v0, v1));
        }
        pm = fmaxf(pm, __shfl_xor(pm, 32));

        // ---- defer-max: rescale only when max grew past threshold ----
        if (!__all(pm - m <= 8.0f)) {
            const float nm    = fmaxf(m, pm);
            const float alpha = __expf(m - nm);
            m = nm;
            lsum *= alpha;
            #pragma unroll
            for (int r = 0; r < 16; ++r) {
                const float ar = __shfl(alpha, (r & 3) + 8 * (r >> 2) + 4 * hi);
                acc0[r] *= ar; acc1[r] *= ar;
            }
        }

        // ---- exp + row sum ----
        float rs = 0.0f;
        #pragma unroll
        for (int r = 0; r < 16; ++r) {
            const float p0 = __expf(st0[r] - m);
            const float p1 = __expf(st1[r] - m);
            st0[r] = p0; st1[r] = p1;
            rs += p0 + p1;
        }
        rs += __shfl_xor(rs, 32);
        lsum += rs;

        // ---- pack P -> bf16 A-fragments via cvt_pk + permlane32_swap ----
        short8 pfr[4];
        #pragma unroll
        for (int sub = 0; sub < 2; ++sub) {
            const f32x16& ps = sub ? st1 : st0;
            uint32_t A0 = cvtpk_bf16(ps[0],  ps[1]);
            uint32_t A1 = cvtpk_bf16(ps[2],  ps[3]);
            uint32_t B0 = cvtpk_bf16(ps[4],  ps[5]);
            uint32_t B1 = cvtpk_bf16(ps[6],  ps[7]);
            uint32_t C0 = cvtpk_bf16(ps[8],  ps[9]);
            uint32_t C1 = cvtpk_bf16(ps[10], ps[11]);
            uint32_t D0 = cvtpk_bf16(ps[12], ps[13]);
            uint32_t D1 = cvtpk_bf16(ps[14], ps[15]);
            pl32swap(A0, B0); pl32swap(A1, B1);
            pl32swap(C0, D0); pl32swap(C1, D1);
            union { uint32_t u[4]; short8 s; } f0, f1;
            f0.u[0] = A0; f0.u[1] = A1; f0.u[2] = B0; f0.u[3] = B1;
            f1.u[0] = C0; f1.u[1] = C1; f1.u[2] = D0; f1.u[3] = D1;
            pfr[sub * 2]     = f0.s;
            pfr[sub * 2 + 1] = f1.s;
        }

        // ---- PV: O += P @ V ----
        #pragma unroll
        for (int kc = 0; kc < 4; ++kc) {
            acc0 = mfma32(pfr[kc], vf0[kc], acc0);
            acc1 = mfma32(pfr[kc], vf1[kc], acc1);
        }
    }

    // ---- epilogue: divide by l (broadcast per row), write bf16 y ----
    const float inv = 1.0f / lsum;
    #pragma unroll
    for (int r = 0; r < 16; ++r) {
        const int row = (r & 3) + 8 * (r >> 2) + 4 * hi;
        const float ir = __shfl(inv, row);
        ushort* yo = y + ((size_t)b * TT + wq0 + row) * DD + h * HD;
        yo[lq]      = f2bf(acc0[r] * ir);
        yo[32 + lq] = f2bf(acc1[r] * ir);
    }
}

// ---------------------------------------------------------------------------
extern "C" void kernel_launch(void* const* d_in, const int* in_sizes, int n_in,
                              void* d_out, int out_size, void* d_ws, size_t ws_size,
                              hipStream_t stream)
{
    const float* x     = (const float*)d_in[0];   // [B,T,D]
    const float* Wqkv  = (const float*)d_in[1];   // [D, 3D]
    const float* bqkv  = (const float*)d_in[2];   // [3D]
    const float* Wproj = (const float*)d_in[3];   // [D, D]
    const float* bproj = (const float*)d_in[4];   // [D]
    float* out = (float*)d_out;                   // [B,T,D]

    ushort* qkv    = (ushort*)d_ws;
    ushort* yb     = qkv    + (size_t)BT * QKV_N;
    ushort* Qb     = yb     + (size_t)BT * DD;
    ushort* Kb     = Qb     + (size_t)BB * HH * TT * HD;
    ushort* Vt     = Kb     + (size_t)BB * HH * TT * HD;
    ushort* xb     = Vt     + (size_t)BB * HH * TT * HD;
    ushort* Wqkvt  = xb     + (size_t)BT * DD;
    ushort* Wprojt = Wqkvt  + (size_t)QKV_N * DD;

    // 0) conversions
    f32_to_bf16<<<(BT * DD / 8 + 255) / 256, 256, 0, stream>>>(x, xb, BT * DD / 8);
    {
        dim3 g1(QKV_N / 64, DD / 64);
        transpose_w_bf16<<<g1, 256, 0, stream>>>(Wqkv, Wqkvt, DD, QKV_N);
        dim3 g2(DD / 64, DD / 64);
        transpose_w_bf16<<<g2, 256, 0, stream>>>(Wproj, Wprojt, DD, DD);
    }
    // 1) QKV projection (bf16 MFMA, bf16 out)
    {
        dim3 grid(QKV_N / 128, BT / 128);
        gemm_bf16_mfma<ushort><<<grid, 256, 0, stream>>>(xb, Wqkvt, bqkv, qkv, BT, QKV_N, DD);
    }
    // 2) RoPE + layout (Q pre-scaled by 1/8)
    {
        dim3 grid(TT / 64, BB * HH);
        rope_convert<<<grid, 256, 0, stream>>>(qkv, Qb, Kb, Vt);
    }
    // 3) Causal attention, wave-independent, no LDS -> yb bf16
    {
        attn_wave32<<<512, 256, 0, stream>>>(Qb, Kb, Vt, yb);
    }
    // 4) Output projection (bf16 MFMA, fp32 out)
    {
        dim3 grid(DD / 128, BT / 128);
        gemm_bf16_mfma<float><<<grid, 256, 0, stream>>>(yb, Wprojt, bproj, out, BT, DD, DD);
    }
}

// Round 6
// 143.611 us; speedup vs baseline: 11.0743x; 1.1601x over previous
//
#include <hip/hip_runtime.h>
#include <hip/hip_bf16.h>
#include <cstdint>

// Problem constants
#define BB 2
#define TT 2048
#define DD 1024
#define HH 16
#define HD 64
#define BT (BB*TT)          // 4096
#define QKV_N (3*DD)        // 3072

typedef __attribute__((ext_vector_type(8))) short  short8;   // 8 bf16 = 16B
typedef __attribute__((ext_vector_type(4))) short  short4x;  // 4 bf16 = 8B
typedef __attribute__((ext_vector_type(4))) float  f32x4;
typedef __attribute__((ext_vector_type(16))) float f32x16;

static __device__ __forceinline__ ushort f2bf(float f) {
    union { float f; uint32_t u; } v; v.f = f;
    uint32_t u = v.u;
    return (ushort)((u + 0x7FFFu + ((u >> 16) & 1u)) >> 16);   // RNE
}
static __device__ __forceinline__ float bf2f(ushort u) {
    union { uint32_t u; float f; } v; v.u = ((uint32_t)u) << 16; return v.f;
}

typedef const __attribute__((address_space(1))) uint32_t* gp1_t;
typedef __attribute__((address_space(3))) uint32_t* lp3_t;
static __device__ __forceinline__ void gload_lds16(const void* g, void* l) {
    __builtin_amdgcn_global_load_lds((gp1_t)g, (lp3_t)l, 16, 0, 0);
}

// pack two f32 -> one u32 of 2 bf16 (lo=a, hi=b)
static __device__ __forceinline__ uint32_t cvtpk_bf16(float a, float b) {
    uint32_t r;
    asm volatile("v_cvt_pk_bf16_f32 %0, %1, %2" : "=v"(r) : "v"(a), "v"(b));
    return r;
}
// swap hi-half lanes of a with lo-half lanes of b
static __device__ __forceinline__ void pl32swap(uint32_t& a, uint32_t& b) {
    asm volatile("v_permlane32_swap_b32 %0, %1" : "+v"(a), "+v"(b));
}
// raw v_exp_f32: 2^x
static __device__ __forceinline__ float fexp2(float x) {
    float r; asm("v_exp_f32 %0, %1" : "=v"(r) : "v"(x)); return r;
}

static __device__ __forceinline__ f32x16 mfma32(short8 a, short8 b, f32x16 c) {
    return __builtin_amdgcn_mfma_f32_32x32x16_bf16(a, b, c, 0, 0, 0);
}

// log2(e) / 8  — folds 1/sqrt(64) and the exp->exp2 conversion into Q
#define QSCALE 0.18033688011112042f

// ---------------------------------------------------------------------------
// fp32 -> bf16 cast, 8 elems/thread
// ---------------------------------------------------------------------------
__global__ __launch_bounds__(256) void f32_to_bf16(
    const float* __restrict__ in, ushort* __restrict__ out, int n8)
{
    const int i = blockIdx.x * 256 + threadIdx.x;
    if (i >= n8) return;
    float4 v0 = *(const float4*)(in + (size_t)i * 8);
    float4 v1 = *(const float4*)(in + (size_t)i * 8 + 4);
    ushort o[8] = {f2bf(v0.x), f2bf(v0.y), f2bf(v0.z), f2bf(v0.w),
                   f2bf(v1.x), f2bf(v1.y), f2bf(v1.z), f2bf(v1.w)};
    *(short8*)(out + (size_t)i * 8) = *(const short8*)o;
}

// ---------------------------------------------------------------------------
// W fp32 [K][N] -> Wt bf16 [N][K]  (64x64 tiles via LDS)
// ---------------------------------------------------------------------------
__global__ __launch_bounds__(256) void transpose_w_bf16(
    const float* __restrict__ W, ushort* __restrict__ Wt, int K, int N)
{
    __shared__ ushort Ws[64][72];
    const int n0 = blockIdx.x * 64;
    const int k0 = blockIdx.y * 64;
    const int tid = threadIdx.x;

    #pragma unroll
    for (int it = 0; it < 4; ++it) {
        const int r  = it * 16 + (tid >> 4);
        const int c4 = (tid & 15) * 4;
        float4 v = *(const float4*)&W[(size_t)(k0 + r) * N + n0 + c4];
        Ws[c4 + 0][r] = f2bf(v.x);
        Ws[c4 + 1][r] = f2bf(v.y);
        Ws[c4 + 2][r] = f2bf(v.z);
        Ws[c4 + 3][r] = f2bf(v.w);
    }
    __syncthreads();
    #pragma unroll
    for (int it = 0; it < 2; ++it) {
        const int rn = it * 32 + (tid >> 3);
        const int c8 = (tid & 7) * 8;
        *(short8*)&Wt[(size_t)(n0 + rn) * K + k0 + c8] = *(const short8*)&Ws[rn][c8];
    }
}

// ---------------------------------------------------------------------------
// bf16 MFMA GEMM: C[M][N] = A[M][K] @ Bt[N][K]^T + bias   (m97 structure)
// ---------------------------------------------------------------------------
template<typename OutT>
__global__ __launch_bounds__(256) void gemm_bf16_mfma(
    const ushort* __restrict__ A, const ushort* __restrict__ Bt,
    const float* __restrict__ bias, OutT* __restrict__ C,
    int M, int N, int K)
{
    __shared__ __align__(16) ushort As[128 * 64];
    __shared__ __align__(16) ushort Bs[128 * 64];

    const int tid = threadIdx.x;
    const int w  = tid >> 6, l = tid & 63;
    const int lr = l & 15,  lg = l >> 4;
    const int wm = w >> 1,  wn = w & 1;
    const int m0 = blockIdx.y * 128;
    const int n0 = blockIdx.x * 128;

    f32x4 acc[4][4] = {};

    for (int k0 = 0; k0 < K; k0 += 64) {
        #pragma unroll
        for (int i = 0; i < 4; ++i) {
            const int f = i * 256 + w * 64 + l;
            const int r = f >> 3, c = f & 7;
            gload_lds16(A + (size_t)(m0 + r) * K + k0 + ((c ^ (r & 7)) << 3),
                        &As[(i * 256 + w * 64) * 8]);
        }
        #pragma unroll
        for (int i = 0; i < 4; ++i) {
            const int f = i * 256 + w * 64 + l;
            const int r = f >> 3, c = f & 7;
            gload_lds16(Bt + (size_t)(n0 + r) * K + k0 + ((c ^ (r & 7)) << 3),
                        &Bs[(i * 256 + w * 64) * 8]);
        }
        __syncthreads();

        #pragma unroll
        for (int kk = 0; kk < 2; ++kk) {
            short8 a[4], b[4];
            #pragma unroll
            for (int mi = 0; mi < 4; ++mi) {
                const int row = wm * 64 + mi * 16 + lr;
                const int c   = kk * 4 + lg;
                a[mi] = *(const short8*)&As[row * 64 + ((c ^ (row & 7)) << 3)];
            }
            #pragma unroll
            for (int ni = 0; ni < 4; ++ni) {
                const int row = wn * 64 + ni * 16 + lr;
                const int c   = kk * 4 + lg;
                b[ni] = *(const short8*)&Bs[row * 64 + ((c ^ (row & 7)) << 3)];
            }
            #pragma unroll
            for (int mi = 0; mi < 4; ++mi)
                #pragma unroll
                for (int ni = 0; ni < 4; ++ni)
                    acc[mi][ni] = __builtin_amdgcn_mfma_f32_16x16x32_bf16(
                        a[mi], b[ni], acc[mi][ni], 0, 0, 0);
        }
        __syncthreads();
    }

    #pragma unroll
    for (int mi = 0; mi < 4; ++mi) {
        #pragma unroll
        for (int ni = 0; ni < 4; ++ni) {
            const int n = n0 + wn * 64 + ni * 16 + lr;
            const float bv = bias[n];
            #pragma unroll
            for (int j = 0; j < 4; ++j) {
                const int m = m0 + wm * 64 + mi * 16 + lg * 4 + j;
                const float v = acc[mi][ni][j] + bv;
                if constexpr (sizeof(OutT) == 2) C[(size_t)m * N + n] = f2bf(v);
                else                             C[(size_t)m * N + n] = v;
            }
        }
    }
}

// ---------------------------------------------------------------------------
// RoPE + layout conversion.
// Out: Qb bf16 [B*H, T, 64] row-major (RoPE'd, scaled by log2e/8).
//      Kswz/Vswz bf16 [B*H][tile=T/64][8 ib][64 lane][8 e] fragment-major:
//        K elem: key = tile*64 + (ib>>2)*32 + (lane&31),
//                dim = (ib&3)*16 + (lane>>5)*8 + e
//        V elem: dim = (ib>>2)*32 + (lane&31),
//                key = tile*64 + (ib&3)*16 + (lane>>5)*8 + e
// Attention then loads each fragment as a fully-coalesced 1KB stream.
// Grid: (T/64, B*H), block 256.
// ---------------------------------------------------------------------------
__global__ __launch_bounds__(256) void rope_convert(
    const ushort* __restrict__ qkv,
    ushort* __restrict__ Qb, ushort* __restrict__ Kswz, ushort* __restrict__ Vswz)
{
    __shared__ __align__(16) ushort Ksl[64][72];   // [key-local][dim]
    __shared__ __align__(16) ushort Vsl[64][72];   // [dim][key-local]

    const int bh = blockIdx.y;
    const int b  = bh >> 4;
    const int h  = bh & 15;
    const int t0 = blockIdx.x * 64;
    const int tid = threadIdx.x;

    // ---- Q (global, row-major) and K (to LDS) with RoPE ----
    {
        const int r  = tid >> 2;
        const int i0 = (tid & 3) * 8;
        const int t  = t0 + r;
        const size_t rowbase = ((size_t)(b * TT + t)) * QKV_N + h * HD;

        float cs[8], sn[8];
        #pragma unroll
        for (int j = 0; j < 8; ++j) {
            const float idx  = (float)(i0 + j);
            const float rate = powf(10000.0f, -idx * (1.0f / 32.0f));
            const float th   = (float)t * rate;
            cs[j] = cosf(th);
            sn[j] = sinf(th);
        }

        // Q: scale by log2e/8, write row-major
        {
            const ushort* p = qkv + rowbase;
            short8 va = *(const short8*)(p + i0);
            short8 vb = *(const short8*)(p + i0 + 32);
            ushort o1[8], o2[8];
            #pragma unroll
            for (int j = 0; j < 8; ++j) {
                const float x1 = bf2f((ushort)va[j]);
                const float x2 = bf2f((ushort)vb[j]);
                o1[j] = f2bf((x1 * cs[j] - x2 * sn[j]) * QSCALE);
                o2[j] = f2bf((x1 * sn[j] + x2 * cs[j]) * QSCALE);
            }
            ushort* outb = Qb + ((size_t)bh * TT + t) * HD;
            *(short8*)(outb + i0)      = *(const short8*)o1;
            *(short8*)(outb + i0 + 32) = *(const short8*)o2;
        }
        // K: unscaled, stage into LDS
        {
            const ushort* p = qkv + rowbase + DD;
            short8 va = *(const short8*)(p + i0);
            short8 vb = *(const short8*)(p + i0 + 32);
            ushort o1[8], o2[8];
            #pragma unroll
            for (int j = 0; j < 8; ++j) {
                const float x1 = bf2f((ushort)va[j]);
                const float x2 = bf2f((ushort)vb[j]);
                o1[j] = f2bf(x1 * cs[j] - x2 * sn[j]);
                o2[j] = f2bf(x1 * sn[j] + x2 * cs[j]);
            }
            *(short8*)&Ksl[r][i0]      = *(const short8*)o1;
            *(short8*)&Ksl[r][i0 + 32] = *(const short8*)o2;
        }
    }

    // ---- V: stage transposed into LDS ----
    #pragma unroll
    for (int it = 0; it < 4; ++it) {
        const int fi  = tid + it * 256;
        const int rv  = fi & 63;
        const int dv4 = (fi >> 6) * 4;
        const ushort* vp = qkv + ((size_t)(b * TT + t0 + rv)) * QKV_N + 2 * DD + h * HD + dv4;
        short4x v4 = *(const short4x*)vp;
        Vsl[dv4 + 0][rv] = (ushort)v4[0];
        Vsl[dv4 + 1][rv] = (ushort)v4[1];
        Vsl[dv4 + 2][rv] = (ushort)v4[2];
        Vsl[dv4 + 3][rv] = (ushort)v4[3];
    }
    __syncthreads();

    // ---- destination-linear coalesced writeout of fragment-major K and V ----
    const size_t tbase = (size_t)bh * TT * HD + (size_t)(t0 >> 6) * 4096;
    #pragma unroll
    for (int it = 0; it < 2; ++it) {
        const int fi = tid + it * 256;     // 0..511 : 8B elem-chunks
        const int ib = fi >> 6;
        const int ll = fi & 63;
        // K: key-local = (ib>>2)*32 + (ll&31), dim = (ib&3)*16 + (ll>>5)*8
        {
            const int kl = ((ib >> 2) << 5) + (ll & 31);
            const int d  = ((ib & 3) << 4) + ((ll >> 5) << 3);
            *(short8*)&Kswz[tbase + (size_t)fi * 8] = *(const short8*)&Ksl[kl][d];
        }
        // V: dim = (ib>>2)*32 + (ll&31), key-local = (ib&3)*16 + (ll>>5)*8
        {
            const int d  = ((ib >> 2) << 5) + (ll & 31);
            const int kl = ((ib & 3) << 4) + ((ll >> 5) << 3);
            *(short8*)&Vswz[tbase + (size_t)fi * 8] = *(const short8*)&Vsl[d][kl];
        }
    }
}

// ---------------------------------------------------------------------------
// Causal flash attention, 32x32x16 MFMA, swapped QK^T, in-register softmax,
// no LDS, fragment-major K/V (all loads fully coalesced: addr = base + l*16).
// exp2-domain softmax (scale folded into Q), defer-max, tree reductions.
// Grid: 512 blocks; block = 4 independent waves {2j, 2j+1, 63-2j, 62-2j}.
// ---------------------------------------------------------------------------
__global__ __launch_bounds__(256) void attn_wave32(
    const ushort* __restrict__ Qb, const ushort* __restrict__ Kswz,
    const ushort* __restrict__ Vswz, ushort* __restrict__ y)
{
    const int bid = blockIdx.x;
    const int bh  = bid & 31;
    const int j   = bid >> 5;
    const int b   = bh >> 4;
    const int h   = bh & 15;
    const int tid = threadIdx.x;
    const int w   = tid >> 6;
    const int l   = tid & 63;
    const int lq  = l & 31;
    const int hi  = l >> 5;

    const int qt  = (w < 2) ? (j * 2 + w) : (63 - (j * 2 + (w - 2)));
    const int wq0 = qt * 32;
    const int qg  = wq0 + lq;     // this lane's q (softmax state owner)

    const ushort* Kbh = Kswz + (size_t)bh * TT * HD;
    const ushort* Vbh = Vswz + (size_t)bh * TT * HD;

    // Q fragments (B-operand), 4 d-chunks of 16
    short8 qf[4];
    {
        const ushort* qrow = Qb + ((size_t)bh * TT + qg) * HD + hi * 8;
        #pragma unroll
        for (int dc = 0; dc < 4; ++dc)
            qf[dc] = *(const short8*)(qrow + dc * 16);
    }

    f32x16 acc0 = {}, acc1 = {};     // O[q-rows][d 0-31], [d 32-63]
    float m = -1e30f, lsum = 0.0f;

    const int nt = (wq0 >> 6) + 1;   // 64-key tiles

    for (int t = 0; t < nt; ++t) {
        const int k0 = t * 64;
        const ushort* kb = Kbh + (size_t)t * 4096 + l * 8;
        const ushort* vb = Vbh + (size_t)t * 4096 + l * 8;

        // ---- fully-coalesced fragment loads (1KB streams) ----
        short8 kf0[4], kf1[4], vf0[4], vf1[4];
        #pragma unroll
        for (int dc = 0; dc < 4; ++dc) {
            kf0[dc] = *(const short8*)(kb + dc * 512);
            kf1[dc] = *(const short8*)(kb + (4 + dc) * 512);
            vf0[dc] = *(const short8*)(vb + dc * 512);
            vf1[dc] = *(const short8*)(vb + (4 + dc) * 512);
        }

        // ---- S^T = K @ Q^T : lane holds 32 keys for q = qg (log2 units) ----
        f32x16 st0 = {}, st1 = {};
        __builtin_amdgcn_s_setprio(1);
        #pragma unroll
        for (int dc = 0; dc < 4; ++dc) {
            st0 = mfma32(kf0[dc], qf[dc], st0);
            st1 = mfma32(kf1[dc], qf[dc], st1);
        }
        __builtin_amdgcn_s_setprio(0);

        // ---- causal mask (only last tile) ----
        if (t == nt - 1) {
            #pragma unroll
            for (int r = 0; r < 16; ++r) {
                const int kk = k0 + (r & 3) + 8 * (r >> 2) + 4 * hi;
                if (kk > qg)      st0[r] = -1e30f;
                if (kk + 32 > qg) st1[r] = -1e30f;
            }
        }

        // ---- row max: tree (depth ~5) + one shfl ----
        float pm;
        {
            float m16[16];
            #pragma unroll
            for (int i = 0; i < 16; ++i) m16[i] = fmaxf(st0[i], st1[i]);
            float m8[8];
            #pragma unroll
            for (int i = 0; i < 8; ++i) m8[i] = fmaxf(m16[i], m16[i + 8]);
            const float a = fmaxf(fmaxf(m8[0], m8[4]), fmaxf(m8[1], m8[5]));
            const float c = fmaxf(fmaxf(m8[2], m8[6]), fmaxf(m8[3], m8[7]));
            pm = fmaxf(a, c);
        }
        pm = fmaxf(pm, __shfl_xor(pm, 32));

        // ---- defer-max: rescale only when max grew past threshold ----
        if (!__all(pm - m <= 8.0f)) {
            const float nm    = fmaxf(m, pm);
            const float alpha = fexp2(m - nm);
            m = nm;
            lsum *= alpha;
            #pragma unroll
            for (int r = 0; r < 16; ++r) {
                const float ar = __shfl(alpha, (r & 3) + 8 * (r >> 2) + 4 * hi);
                acc0[r] *= ar; acc1[r] *= ar;
            }
        }

        // ---- exp2 + tree sum ----
        #pragma unroll
        for (int r = 0; r < 16; ++r) {
            st0[r] = fexp2(st0[r] - m);
            st1[r] = fexp2(st1[r] - m);
        }
        float rs;
        {
            float s16[16];
            #pragma unroll
            for (int i = 0; i < 16; ++i) s16[i] = st0[i] + st1[i];
            float s8[8];
            #pragma unroll
            for (int i = 0; i < 8; ++i) s8[i] = s16[i] + s16[i + 8];
            rs = ((s8[0] + s8[4]) + (s8[1] + s8[5]))
               + ((s8[2] + s8[6]) + (s8[3] + s8[7]));
        }
        rs += __shfl_xor(rs, 32);
        lsum += rs;

        // ---- pack P -> bf16 A-fragments via cvt_pk + permlane32_swap ----
        short8 pfr[4];
        #pragma unroll
        for (int sub = 0; sub < 2; ++sub) {
            const f32x16& ps = sub ? st1 : st0;
            uint32_t A0 = cvtpk_bf16(ps[0],  ps[1]);
            uint32_t A1 = cvtpk_bf16(ps[2],  ps[3]);
            uint32_t B0 = cvtpk_bf16(ps[4],  ps[5]);
            uint32_t B1 = cvtpk_bf16(ps[6],  ps[7]);
            uint32_t C0 = cvtpk_bf16(ps[8],  ps[9]);
            uint32_t C1 = cvtpk_bf16(ps[10], ps[11]);
            uint32_t D0 = cvtpk_bf16(ps[12], ps[13]);
            uint32_t D1 = cvtpk_bf16(ps[14], ps[15]);
            pl32swap(A0, B0); pl32swap(A1, B1);
            pl32swap(C0, D0); pl32swap(C1, D1);
            union { uint32_t u[4]; short8 s; } f0, f1;
            f0.u[0] = A0; f0.u[1] = A1; f0.u[2] = B0; f0.u[3] = B1;
            f1.u[0] = C0; f1.u[1] = C1; f1.u[2] = D0; f1.u[3] = D1;
            pfr[sub * 2]     = f0.s;
            pfr[sub * 2 + 1] = f1.s;
        }

        // ---- PV: O += P @ V ----
        __builtin_amdgcn_s_setprio(1);
        #pragma unroll
        for (int kc = 0; kc < 4; ++kc) {
            acc0 = mfma32(pfr[kc], vf0[kc], acc0);
            acc1 = mfma32(pfr[kc], vf1[kc], acc1);
        }
        __builtin_amdgcn_s_setprio(0);
    }

    // ---- epilogue: divide by l (broadcast per row), write bf16 y ----
    const float inv = 1.0f / lsum;
    #pragma unroll
    for (int r = 0; r < 16; ++r) {
        const int row = (r & 3) + 8 * (r >> 2) + 4 * hi;
        const float ir = __shfl(inv, row);
        ushort* yo = y + ((size_t)b * TT + wq0 + row) * DD + h * HD;
        yo[lq]      = f2bf(acc0[r] * ir);
        yo[32 + lq] = f2bf(acc1[r] * ir);
    }
}

// ---------------------------------------------------------------------------
extern "C" void kernel_launch(void* const* d_in, const int* in_sizes, int n_in,
                              void* d_out, int out_size, void* d_ws, size_t ws_size,
                              hipStream_t stream)
{
    const float* x     = (const float*)d_in[0];   // [B,T,D]
    const float* Wqkv  = (const float*)d_in[1];   // [D, 3D]
    const float* bqkv  = (const float*)d_in[2];   // [3D]
    const float* Wproj = (const float*)d_in[3];   // [D, D]
    const float* bproj = (const float*)d_in[4];   // [D]
    float* out = (float*)d_out;                   // [B,T,D]

    ushort* qkv    = (ushort*)d_ws;
    ushort* yb     = qkv    + (size_t)BT * QKV_N;
    ushort* Qb     = yb     + (size_t)BT * DD;
    ushort* Kswz   = Qb     + (size_t)BB * HH * TT * HD;
    ushort* Vswz   = Kswz   + (size_t)BB * HH * TT * HD;
    ushort* xb     = Vswz   + (size_t)BB * HH * TT * HD;
    ushort* Wqkvt  = xb     + (size_t)BT * DD;
    ushort* Wprojt = Wqkvt  + (size_t)QKV_N * DD;

    // 0) conversions
    f32_to_bf16<<<(BT * DD / 8 + 255) / 256, 256, 0, stream>>>(x, xb, BT * DD / 8);
    {
        dim3 g1(QKV_N / 64, DD / 64);
        transpose_w_bf16<<<g1, 256, 0, stream>>>(Wqkv, Wqkvt, DD, QKV_N);
        dim3 g2(DD / 64, DD / 64);
        transpose_w_bf16<<<g2, 256, 0, stream>>>(Wproj, Wprojt, DD, DD);
    }
    // 1) QKV projection (bf16 MFMA, bf16 out)
    {
        dim3 grid(QKV_N / 128, BT / 128);
        gemm_bf16_mfma<ushort><<<grid, 256, 0, stream>>>(xb, Wqkvt, bqkv, qkv, BT, QKV_N, DD);
    }
    // 2) RoPE + fragment-major K/V layout (Q pre-scaled by log2e/8)
    {
        dim3 grid(TT / 64, BB * HH);
        rope_convert<<<grid, 256, 0, stream>>>(qkv, Qb, Kswz, Vswz);
    }
    // 3) Causal attention, wave-independent, coalesced fragment loads
    {
        attn_wave32<<<512, 256, 0, stream>>>(Qb, Kswz, Vswz, yb);
    }
    // 4) Output projection (bf16 MFMA, fp32 out)
    {
        dim3 grid(DD / 128, BT / 128);
        gemm_bf16_mfma<float><<<grid, 256, 0, stream>>>(yb, Wprojt, bproj, out, BT, DD, DD);
    }
}

// Round 7
// 123.809 us; speedup vs baseline: 12.8456x; 1.1599x over previous
//
#include <hip/hip_runtime.h>
#include <hip/hip_bf16.h>
#include <cstdint>

// Problem constants
#define BB 2
#define TT 2048
#define DD 1024
#define HH 16
#define HD 64
#define BT (BB*TT)          // 4096
#define QKV_N (3*DD)        // 3072

typedef __attribute__((ext_vector_type(8))) short  short8;   // 8 bf16 = 16B
typedef __attribute__((ext_vector_type(4))) float  f32x4;
typedef __attribute__((ext_vector_type(16))) float f32x16;

static __device__ __forceinline__ ushort f2bf(float f) {
    union { float f; uint32_t u; } v; v.f = f;
    uint32_t u = v.u;
    return (ushort)((u + 0x7FFFu + ((u >> 16) & 1u)) >> 16);   // RNE
}

typedef const __attribute__((address_space(1))) uint32_t* gp1_t;
typedef __attribute__((address_space(3))) uint32_t* lp3_t;
static __device__ __forceinline__ void gload_lds16(const void* g, void* l) {
    __builtin_amdgcn_global_load_lds((gp1_t)g, (lp3_t)l, 16, 0, 0);
}

// pack two f32 -> one u32 of 2 bf16 (lo=a, hi=b)
static __device__ __forceinline__ uint32_t cvtpk_bf16(float a, float b) {
    uint32_t r;
    asm volatile("v_cvt_pk_bf16_f32 %0, %1, %2" : "=v"(r) : "v"(a), "v"(b));
    return r;
}
// swap hi-half lanes of a with lo-half lanes of b
static __device__ __forceinline__ void pl32swap(uint32_t& a, uint32_t& b) {
    asm volatile("v_permlane32_swap_b32 %0, %1" : "+v"(a), "+v"(b));
}
// raw v_exp_f32: 2^x
static __device__ __forceinline__ float fexp2(float x) {
    float r; asm("v_exp_f32 %0, %1" : "=v"(r) : "v"(x)); return r;
}

static __device__ __forceinline__ f32x16 mfma32(short8 a, short8 b, f32x16 c) {
    return __builtin_amdgcn_mfma_f32_32x32x16_bf16(a, b, c, 0, 0, 0);
}

// log2(e) / 8  — folds 1/sqrt(64) and the exp->exp2 conversion into Q
#define QSCALE 0.18033688011112042f

// ---------------------------------------------------------------------------
// fp32 -> bf16 cast, 8 elems/thread
// ---------------------------------------------------------------------------
__global__ __launch_bounds__(256) void f32_to_bf16(
    const float* __restrict__ in, ushort* __restrict__ out, int n8)
{
    const int i = blockIdx.x * 256 + threadIdx.x;
    if (i >= n8) return;
    float4 v0 = *(const float4*)(in + (size_t)i * 8);
    float4 v1 = *(const float4*)(in + (size_t)i * 8 + 4);
    ushort o[8] = {f2bf(v0.x), f2bf(v0.y), f2bf(v0.z), f2bf(v0.w),
                   f2bf(v1.x), f2bf(v1.y), f2bf(v1.z), f2bf(v1.w)};
    *(short8*)(out + (size_t)i * 8) = *(const short8*)o;
}

// ---------------------------------------------------------------------------
// cos/sin table: ctab[t][i] = (cos(t*rate_i), sin(t*rate_i)), i in [0,32)
// ---------------------------------------------------------------------------
__global__ __launch_bounds__(256) void rope_tab(float2* __restrict__ ctab)
{
    const int idx = blockIdx.x * 256 + threadIdx.x;   // t*32 + i
    const int i = idx & 31;
    const int t = idx >> 5;
    const float rate = powf(10000.0f, -(float)i * (1.0f / 32.0f));
    const float th = (float)t * rate;
    ctab[idx] = make_float2(cosf(th), sinf(th));
}

// ---------------------------------------------------------------------------
// W fp32 [K][N] -> Wt bf16 [N][K]  (64x64 tiles via LDS)
// ---------------------------------------------------------------------------
__global__ __launch_bounds__(256) void transpose_w_bf16(
    const float* __restrict__ W, ushort* __restrict__ Wt, int K, int N)
{
    __shared__ ushort Ws[64][72];
    const int n0 = blockIdx.x * 64;
    const int k0 = blockIdx.y * 64;
    const int tid = threadIdx.x;

    #pragma unroll
    for (int it = 0; it < 4; ++it) {
        const int r  = it * 16 + (tid >> 4);
        const int c4 = (tid & 15) * 4;
        float4 v = *(const float4*)&W[(size_t)(k0 + r) * N + n0 + c4];
        Ws[c4 + 0][r] = f2bf(v.x);
        Ws[c4 + 1][r] = f2bf(v.y);
        Ws[c4 + 2][r] = f2bf(v.z);
        Ws[c4 + 3][r] = f2bf(v.w);
    }
    __syncthreads();
    #pragma unroll
    for (int it = 0; it < 2; ++it) {
        const int rn = it * 32 + (tid >> 3);
        const int c8 = (tid & 7) * 8;
        *(short8*)&Wt[(size_t)(n0 + rn) * K + k0 + c8] = *(const short8*)&Ws[rn][c8];
    }
}

// ---------------------------------------------------------------------------
// Proj GEMM: C[M][N] = A[M][K] @ Bt[N][K]^T + bias (fp32 out), m97 structure,
// 1-D grid with XCD-aware bijective swizzle (nwg % 8 == 0).
// ---------------------------------------------------------------------------
__global__ __launch_bounds__(256) void gemm_proj(
    const ushort* __restrict__ A, const ushort* __restrict__ Bt,
    const float* __restrict__ bias, float* __restrict__ C,
    int M, int N, int K)
{
    __shared__ __align__(16) ushort As[128 * 64];
    __shared__ __align__(16) ushort Bs[128 * 64];

    const int nbx = N >> 7;
    const int nwg = (M >> 7) * nbx;
    const int cpx = nwg >> 3;
    const int bid = blockIdx.x;
    const int lb  = (bid & 7) * cpx + (bid >> 3);
    const int n0 = (lb % nbx) * 128;
    const int m0 = (lb / nbx) * 128;

    const int tid = threadIdx.x;
    const int w  = tid >> 6, l = tid & 63;
    const int lr = l & 15,  lg = l >> 4;
    const int wm = w >> 1,  wn = w & 1;

    f32x4 acc[4][4] = {};

    for (int k0 = 0; k0 < K; k0 += 64) {
        #pragma unroll
        for (int i = 0; i < 4; ++i) {
            const int f = i * 256 + w * 64 + l;
            const int r = f >> 3, c = f & 7;
            gload_lds16(A + (size_t)(m0 + r) * K + k0 + ((c ^ (r & 7)) << 3),
                        &As[(i * 256 + w * 64) * 8]);
        }
        #pragma unroll
        for (int i = 0; i < 4; ++i) {
            const int f = i * 256 + w * 64 + l;
            const int r = f >> 3, c = f & 7;
            gload_lds16(Bt + (size_t)(n0 + r) * K + k0 + ((c ^ (r & 7)) << 3),
                        &Bs[(i * 256 + w * 64) * 8]);
        }
        __syncthreads();

        #pragma unroll
        for (int kk = 0; kk < 2; ++kk) {
            short8 a[4], b[4];
            #pragma unroll
            for (int mi = 0; mi < 4; ++mi) {
                const int row = wm * 64 + mi * 16 + lr;
                const int c   = kk * 4 + lg;
                a[mi] = *(const short8*)&As[row * 64 + ((c ^ (row & 7)) << 3)];
            }
            #pragma unroll
            for (int ni = 0; ni < 4; ++ni) {
                const int row = wn * 64 + ni * 16 + lr;
                const int c   = kk * 4 + lg;
                b[ni] = *(const short8*)&Bs[row * 64 + ((c ^ (row & 7)) << 3)];
            }
            #pragma unroll
            for (int mi = 0; mi < 4; ++mi)
                #pragma unroll
                for (int ni = 0; ni < 4; ++ni)
                    acc[mi][ni] = __builtin_amdgcn_mfma_f32_16x16x32_bf16(
                        a[mi], b[ni], acc[mi][ni], 0, 0, 0);
        }
        __syncthreads();
    }

    #pragma unroll
    for (int mi = 0; mi < 4; ++mi) {
        #pragma unroll
        for (int ni = 0; ni < 4; ++ni) {
            const int n = n0 + wn * 64 + ni * 16 + lr;
            const float bv = bias[n];
            #pragma unroll
            for (int j = 0; j < 4; ++j) {
                const int m = m0 + wm * 64 + mi * 16 + lg * 4 + j;
                C[(size_t)m * N + n] = acc[mi][ni][j] + bv;
            }
        }
    }
}

// ---------------------------------------------------------------------------
// Fused QKV GEMM: qkv = xb @ Wqkvt^T + bias, then in-epilogue RoPE + direct
// write to Qb (row-major, *QSCALE), Kswz / Vswz (fragment-major, layouts
// carried over from the verified round-6 writer). XCD-swizzled 1-D grid.
// RoPE pairs (d, d+32) = acc cols (ni, ni+2) -> same lane, pure register math.
// ---------------------------------------------------------------------------
__global__ __launch_bounds__(256) void gemm_qkv_fused(
    const ushort* __restrict__ A,      // xb [4096][1024]
    const ushort* __restrict__ Bt,     // Wqkvt [3072][1024]
    const float*  __restrict__ bias,   // [3072]
    const float2* __restrict__ ctab,   // [2048][32]
    ushort* __restrict__ Qb, ushort* __restrict__ Kswz, ushort* __restrict__ Vswz)
{
    __shared__ __align__(16) ushort As[128 * 64];
    __shared__ __align__(16) ushort Bs[128 * 64];

    const int nbx = QKV_N >> 7;          // 24
    const int cpx = ((BT >> 7) * nbx) >> 3;   // 96
    const int bid = blockIdx.x;
    const int lb  = (bid & 7) * cpx + (bid >> 3);
    const int n0 = (lb % nbx) * 128;
    const int m0 = (lb / nbx) * 128;

    const int tid = threadIdx.x;
    const int w  = tid >> 6, l = tid & 63;
    const int lr = l & 15,  lg = l >> 4;
    const int wm = w >> 1,  wn = w & 1;

    f32x4 acc[4][4] = {};

    for (int k0 = 0; k0 < DD; k0 += 64) {
        #pragma unroll
        for (int i = 0; i < 4; ++i) {
            const int f = i * 256 + w * 64 + l;
            const int r = f >> 3, c = f & 7;
            gload_lds16(A + (size_t)(m0 + r) * DD + k0 + ((c ^ (r & 7)) << 3),
                        &As[(i * 256 + w * 64) * 8]);
        }
        #pragma unroll
        for (int i = 0; i < 4; ++i) {
            const int f = i * 256 + w * 64 + l;
            const int r = f >> 3, c = f & 7;
            gload_lds16(Bt + (size_t)(n0 + r) * DD + k0 + ((c ^ (r & 7)) << 3),
                        &Bs[(i * 256 + w * 64) * 8]);
        }
        __syncthreads();

        #pragma unroll
        for (int kk = 0; kk < 2; ++kk) {
            short8 a[4], b[4];
            #pragma unroll
            for (int mi = 0; mi < 4; ++mi) {
                const int row = wm * 64 + mi * 16 + lr;
                const int c   = kk * 4 + lg;
                a[mi] = *(const short8*)&As[row * 64 + ((c ^ (row & 7)) << 3)];
            }
            #pragma unroll
            for (int ni = 0; ni < 4; ++ni) {
                const int row = wn * 64 + ni * 16 + lr;
                const int c   = kk * 4 + lg;
                b[ni] = *(const short8*)&Bs[row * 64 + ((c ^ (row & 7)) << 3)];
            }
            #pragma unroll
            for (int mi = 0; mi < 4; ++mi)
                #pragma unroll
                for (int ni = 0; ni < 4; ++ni)
                    acc[mi][ni] = __builtin_amdgcn_mfma_f32_16x16x32_bf16(
                        a[mi], b[ni], acc[mi][ni], 0, 0, 0);
        }
        __syncthreads();
    }

    // ---- fused epilogue: bias + RoPE + layout writes ----
    const int g64  = n0 + wn * 64;        // 64-aligned column group
    const int part = g64 >> 10;           // 0=q, 1=k, 2=v  (wave-uniform)
    const int h    = (g64 & 1023) >> 6;

    float bv[4];
    #pragma unroll
    for (int ni = 0; ni < 4; ++ni) bv[ni] = bias[g64 + ni * 16 + lr];

    #pragma unroll
    for (int mi = 0; mi < 4; ++mi) {
        #pragma unroll
        for (int j = 0; j < 4; ++j) {
            const int m  = m0 + wm * 64 + mi * 16 + lg * 4 + j;
            const int bb = m >> 11;
            const int t  = m & (TT - 1);
            const int bh = bb * HH + h;
            const float v0 = acc[mi][0][j] + bv[0];
            const float v1 = acc[mi][1][j] + bv[1];
            const float v2 = acc[mi][2][j] + bv[2];
            const float v3 = acc[mi][3][j] + bv[3];

            if (part == 2) {
                // V: fragment-major (no RoPE)
                ushort* vb = Vswz + (size_t)bh * (TT * HD) + (t >> 6) * 4096
                           + ((t & 63) >> 4) * 512 + ((t >> 3) & 1) * 256
                           + (t & 7) + lr * 8;
                vb[0]    = f2bf(v0);
                vb[128]  = f2bf(v1);
                vb[2048] = f2bf(v2);
                vb[2176] = f2bf(v3);
            } else {
                const float2 cs0 = ctab[t * 32 + lr];
                const float2 cs1 = ctab[t * 32 + 16 + lr];
                float r0 = v0 * cs0.x - v2 * cs0.y;
                float r2 = v0 * cs0.y + v2 * cs0.x;
                float r1 = v1 * cs1.x - v3 * cs1.y;
                float r3 = v1 * cs1.y + v3 * cs1.x;
                if (part == 0) {
                    r0 *= QSCALE; r1 *= QSCALE; r2 *= QSCALE; r3 *= QSCALE;
                    ushort* qb = Qb + (size_t)bh * (TT * HD) + t * HD + lr;
                    qb[0]  = f2bf(r0);
                    qb[16] = f2bf(r1);
                    qb[32] = f2bf(r2);
                    qb[48] = f2bf(r3);
                } else {
                    // K: fragment-major
                    ushort* kb = Kswz + (size_t)bh * (TT * HD) + (t >> 6) * 4096
                               + ((t >> 5) & 1) * 2048 + (t & 31) * 8
                               + ((lr >> 3) & 1) * 256 + (lr & 7);
                    kb[0]    = f2bf(r0);
                    kb[512]  = f2bf(r1);
                    kb[1024] = f2bf(r2);
                    kb[1536] = f2bf(r3);
                }
            }
        }
    }
}

// ---------------------------------------------------------------------------
// Causal flash attention, 32x32x16 MFMA, swapped QK^T, in-register softmax,
// no LDS, fragment-major K/V (all loads fully coalesced: addr = base + l*16).
// exp2-domain softmax (scale folded into Q), defer-max, tree reductions.
// Grid: 512 blocks; block = 4 independent waves {2j, 2j+1, 63-2j, 62-2j}.
// ---------------------------------------------------------------------------
__global__ __launch_bounds__(256) void attn_wave32(
    const ushort* __restrict__ Qb, const ushort* __restrict__ Kswz,
    const ushort* __restrict__ Vswz, ushort* __restrict__ y)
{
    const int bid = blockIdx.x;
    const int bh  = bid & 31;
    const int j   = bid >> 5;
    const int b   = bh >> 4;
    const int h   = bh & 15;
    const int tid = threadIdx.x;
    const int w   = tid >> 6;
    const int l   = tid & 63;
    const int lq  = l & 31;
    const int hi  = l >> 5;

    const int qt  = (w < 2) ? (j * 2 + w) : (63 - (j * 2 + (w - 2)));
    const int wq0 = qt * 32;
    const int qg  = wq0 + lq;     // this lane's q (softmax state owner)

    const ushort* Kbh = Kswz + (size_t)bh * TT * HD;
    const ushort* Vbh = Vswz + (size_t)bh * TT * HD;

    // Q fragments (B-operand), 4 d-chunks of 16
    short8 qf[4];
    {
        const ushort* qrow = Qb + ((size_t)bh * TT + qg) * HD + hi * 8;
        #pragma unroll
        for (int dc = 0; dc < 4; ++dc)
            qf[dc] = *(const short8*)(qrow + dc * 16);
    }

    f32x16 acc0 = {}, acc1 = {};     // O[q-rows][d 0-31], [d 32-63]
    float m = -1e30f, lsum = 0.0f;

    const int nt = (wq0 >> 6) + 1;   // 64-key tiles

    for (int t = 0; t < nt; ++t) {
        const int k0 = t * 64;
        const ushort* kb = Kbh + (size_t)t * 4096 + l * 8;
        const ushort* vb = Vbh + (size_t)t * 4096 + l * 8;

        // ---- fully-coalesced fragment loads (1KB streams) ----
        short8 kf0[4], kf1[4], vf0[4], vf1[4];
        #pragma unroll
        for (int dc = 0; dc < 4; ++dc) {
            kf0[dc] = *(const short8*)(kb + dc * 512);
            kf1[dc] = *(const short8*)(kb + (4 + dc) * 512);
            vf0[dc] = *(const short8*)(vb + dc * 512);
            vf1[dc] = *(const short8*)(vb + (4 + dc) * 512);
        }

        // ---- S^T = K @ Q^T : lane holds 32 keys for q = qg (log2 units) ----
        f32x16 st0 = {}, st1 = {};
        __builtin_amdgcn_s_setprio(1);
        #pragma unroll
        for (int dc = 0; dc < 4; ++dc) {
            st0 = mfma32(kf0[dc], qf[dc], st0);
            st1 = mfma32(kf1[dc], qf[dc], st1);
        }
        __builtin_amdgcn_s_setprio(0);

        // ---- causal mask (only last tile) ----
        if (t == nt - 1) {
            #pragma unroll
            for (int r = 0; r < 16; ++r) {
                const int kk = k0 + (r & 3) + 8 * (r >> 2) + 4 * hi;
                if (kk > qg)      st0[r] = -1e30f;
                if (kk + 32 > qg) st1[r] = -1e30f;
            }
        }

        // ---- row max: tree + one shfl ----
        float pm;
        {
            float m16[16];
            #pragma unroll
            for (int i = 0; i < 16; ++i) m16[i] = fmaxf(st0[i], st1[i]);
            float m8[8];
            #pragma unroll
            for (int i = 0; i < 8; ++i) m8[i] = fmaxf(m16[i], m16[i + 8]);
            const float a = fmaxf(fmaxf(m8[0], m8[4]), fmaxf(m8[1], m8[5]));
            const float c = fmaxf(fmaxf(m8[2], m8[6]), fmaxf(m8[3], m8[7]));
            pm = fmaxf(a, c);
        }
        pm = fmaxf(pm, __shfl_xor(pm, 32));

        // ---- defer-max: rescale only when max grew past threshold ----
        if (!__all(pm - m <= 8.0f)) {
            const float nm    = fmaxf(m, pm);
            const float alpha = fexp2(m - nm);
            m = nm;
            lsum *= alpha;
            #pragma unroll
            for (int r = 0; r < 16; ++r) {
                const float ar = __shfl(alpha, (r & 3) + 8 * (r >> 2) + 4 * hi);
                acc0[r] *= ar; acc1[r] *= ar;
            }
        }

        // ---- exp2 + tree sum ----
        #pragma unroll
        for (int r = 0; r < 16; ++r) {
            st0[r] = fexp2(st0[r] - m);
            st1[r] = fexp2(st1[r] - m);
        }
        float rs;
        {
            float s16[16];
            #pragma unroll
            for (int i = 0; i < 16; ++i) s16[i] = st0[i] + st1[i];
            float s8[8];
            #pragma unroll
            for (int i = 0; i < 8; ++i) s8[i] = s16[i] + s16[i + 8];
            rs = ((s8[0] + s8[4]) + (s8[1] + s8[5]))
               + ((s8[2] + s8[6]) + (s8[3] + s8[7]));
        }
        rs += __shfl_xor(rs, 32);
        lsum += rs;

        // ---- pack P -> bf16 A-fragments via cvt_pk + permlane32_swap ----
        short8 pfr[4];
        #pragma unroll
        for (int sub = 0; sub < 2; ++sub) {
            const f32x16& ps = sub ? st1 : st0;
            uint32_t A0 = cvtpk_bf16(ps[0],  ps[1]);
            uint32_t A1 = cvtpk_bf16(ps[2],  ps[3]);
            uint32_t B0 = cvtpk_bf16(ps[4],  ps[5]);
            uint32_t B1 = cvtpk_bf16(ps[6],  ps[7]);
            uint32_t C0 = cvtpk_bf16(ps[8],  ps[9]);
            uint32_t C1 = cvtpk_bf16(ps[10], ps[11]);
            uint32_t D0 = cvtpk_bf16(ps[12], ps[13]);
            uint32_t D1 = cvtpk_bf16(ps[14], ps[15]);
            pl32swap(A0, B0); pl32swap(A1, B1);
            pl32swap(C0, D0); pl32swap(C1, D1);
            union { uint32_t u[4]; short8 s; } f0, f1;
            f0.u[0] = A0; f0.u[1] = A1; f0.u[2] = B0; f0.u[3] = B1;
            f1.u[0] = C0; f1.u[1] = C1; f1.u[2] = D0; f1.u[3] = D1;
            pfr[sub * 2]     = f0.s;
            pfr[sub * 2 + 1] = f1.s;
        }

        // ---- PV: O += P @ V ----
        __builtin_amdgcn_s_setprio(1);
        #pragma unroll
        for (int kc = 0; kc < 4; ++kc) {
            acc0 = mfma32(pfr[kc], vf0[kc], acc0);
            acc1 = mfma32(pfr[kc], vf1[kc], acc1);
        }
        __builtin_amdgcn_s_setprio(0);
    }

    // ---- epilogue: divide by l (broadcast per row), write bf16 y ----
    const float inv = 1.0f / lsum;
    #pragma unroll
    for (int r = 0; r < 16; ++r) {
        const int row = (r & 3) + 8 * (r >> 2) + 4 * hi;
        const float ir = __shfl(inv, row);
        ushort* yo = y + ((size_t)b * TT + wq0 + row) * DD + h * HD;
        yo[lq]      = f2bf(acc0[r] * ir);
        yo[32 + lq] = f2bf(acc1[r] * ir);
    }
}

// ---------------------------------------------------------------------------
extern "C" void kernel_launch(void* const* d_in, const int* in_sizes, int n_in,
                              void* d_out, int out_size, void* d_ws, size_t ws_size,
                              hipStream_t stream)
{
    const float* x     = (const float*)d_in[0];   // [B,T,D]
    const float* Wqkv  = (const float*)d_in[1];   // [D, 3D]
    const float* bqkv  = (const float*)d_in[2];   // [3D]
    const float* Wproj = (const float*)d_in[3];   // [D, D]
    const float* bproj = (const float*)d_in[4];   // [D]
    float* out = (float*)d_out;                   // [B,T,D]

    // Workspace (ushort units unless noted): yb 8MB | Qb 8 | Kswz 8 | Vswz 8 |
    //   xb 8 | Wqkvt 6 | Wprojt 2 | ctab 0.5MB(f32x2)  ~= 49 MB
    ushort* yb     = (ushort*)d_ws;
    ushort* Qb     = yb     + (size_t)BT * DD;
    ushort* Kswz   = Qb     + (size_t)BB * HH * TT * HD;
    ushort* Vswz   = Kswz   + (size_t)BB * HH * TT * HD;
    ushort* xb     = Vswz   + (size_t)BB * HH * TT * HD;
    ushort* Wqkvt  = xb     + (size_t)BT * DD;
    ushort* Wprojt = Wqkvt  + (size_t)QKV_N * DD;
    float2* ctab   = (float2*)(Wprojt + (size_t)DD * DD);

    // 0) conversions + tables
    f32_to_bf16<<<(BT * DD / 8 + 255) / 256, 256, 0, stream>>>(x, xb, BT * DD / 8);
    rope_tab<<<TT * 32 / 256, 256, 0, stream>>>(ctab);
    {
        dim3 g1(QKV_N / 64, DD / 64);
        transpose_w_bf16<<<g1, 256, 0, stream>>>(Wqkv, Wqkvt, DD, QKV_N);
        dim3 g2(DD / 64, DD / 64);
        transpose_w_bf16<<<g2, 256, 0, stream>>>(Wproj, Wprojt, DD, DD);
    }
    // 1) Fused QKV GEMM + bias + RoPE + layout (writes Qb/Kswz/Vswz directly)
    {
        gemm_qkv_fused<<<(BT / 128) * (QKV_N / 128), 256, 0, stream>>>(
            xb, Wqkvt, bqkv, ctab, Qb, Kswz, Vswz);
    }
    // 2) Causal attention, wave-independent, coalesced fragment loads
    {
        attn_wave32<<<512, 256, 0, stream>>>(Qb, Kswz, Vswz, yb);
    }
    // 3) Output projection (bf16 MFMA, fp32 out), XCD-swizzled
    {
        gemm_proj<<<(BT / 128) * (DD / 128), 256, 0, stream>>>(
            yb, Wprojt, bproj, out, BT, DD, DD);
    }
}

// Round 8
// 118.986 us; speedup vs baseline: 13.3663x; 1.0405x over previous
//
#include <hip/hip_runtime.h>
#include <hip/hip_bf16.h>
#include <cstdint>

// Problem constants
#define BB 2
#define TT 2048
#define DD 1024
#define HH 16
#define HD 64
#define BT (BB*TT)          // 4096
#define QKV_N (3*DD)        // 3072

typedef __attribute__((ext_vector_type(8))) short  short8;   // 8 bf16 = 16B
typedef __attribute__((ext_vector_type(4))) float  f32x4;
typedef __attribute__((ext_vector_type(16))) float f32x16;

static __device__ __forceinline__ ushort f2bf(float f) {
    union { float f; uint32_t u; } v; v.f = f;
    uint32_t u = v.u;
    return (ushort)((u + 0x7FFFu + ((u >> 16) & 1u)) >> 16);   // RNE
}

typedef const __attribute__((address_space(1))) uint32_t* gp1_t;
typedef __attribute__((address_space(3))) uint32_t* lp3_t;
static __device__ __forceinline__ void gload_lds16(const void* g, void* l) {
    __builtin_amdgcn_global_load_lds((gp1_t)g, (lp3_t)l, 16, 0, 0);
}

// pack two f32 -> one u32 of 2 bf16 (lo=a, hi=b)
static __device__ __forceinline__ uint32_t cvtpk_bf16(float a, float b) {
    uint32_t r;
    asm volatile("v_cvt_pk_bf16_f32 %0, %1, %2" : "=v"(r) : "v"(a), "v"(b));
    return r;
}
// swap hi-half lanes of a with lo-half lanes of b
static __device__ __forceinline__ void pl32swap(uint32_t& a, uint32_t& b) {
    asm volatile("v_permlane32_swap_b32 %0, %1" : "+v"(a), "+v"(b));
}
// raw v_exp_f32: 2^x
static __device__ __forceinline__ float fexp2(float x) {
    float r; asm("v_exp_f32 %0, %1" : "=v"(r) : "v"(x)); return r;
}

static __device__ __forceinline__ f32x16 mfma32(short8 a, short8 b, f32x16 c) {
    return __builtin_amdgcn_mfma_f32_32x32x16_bf16(a, b, c, 0, 0, 0);
}

// log2(e) / 8  — folds 1/sqrt(64) and the exp->exp2 conversion into Q
#define QSCALE 0.18033688011112042f

// ---------------------------------------------------------------------------
// fp32 -> bf16 cast, 8 elems/thread
// ---------------------------------------------------------------------------
__global__ __launch_bounds__(256) void f32_to_bf16(
    const float* __restrict__ in, ushort* __restrict__ out, int n8)
{
    const int i = blockIdx.x * 256 + threadIdx.x;
    if (i >= n8) return;
    float4 v0 = *(const float4*)(in + (size_t)i * 8);
    float4 v1 = *(const float4*)(in + (size_t)i * 8 + 4);
    ushort o[8] = {f2bf(v0.x), f2bf(v0.y), f2bf(v0.z), f2bf(v0.w),
                   f2bf(v1.x), f2bf(v1.y), f2bf(v1.z), f2bf(v1.w)};
    *(short8*)(out + (size_t)i * 8) = *(const short8*)o;
}

// ---------------------------------------------------------------------------
// cos/sin table: ctab[t][i] = (cos(t*rate_i), sin(t*rate_i)), i in [0,32)
// ---------------------------------------------------------------------------
__global__ __launch_bounds__(256) void rope_tab(float2* __restrict__ ctab)
{
    const int idx = blockIdx.x * 256 + threadIdx.x;   // t*32 + i
    const int i = idx & 31;
    const int t = idx >> 5;
    const float rate = powf(10000.0f, -(float)i * (1.0f / 32.0f));
    const float th = (float)t * rate;
    ctab[idx] = make_float2(cosf(th), sinf(th));
}

// ---------------------------------------------------------------------------
// W fp32 [K][N] -> Wt bf16 [N][K]  (64x64 tiles via LDS)
// ---------------------------------------------------------------------------
__global__ __launch_bounds__(256) void transpose_w_bf16(
    const float* __restrict__ W, ushort* __restrict__ Wt, int K, int N)
{
    __shared__ ushort Ws[64][72];
    const int n0 = blockIdx.x * 64;
    const int k0 = blockIdx.y * 64;
    const int tid = threadIdx.x;

    #pragma unroll
    for (int it = 0; it < 4; ++it) {
        const int r  = it * 16 + (tid >> 4);
        const int c4 = (tid & 15) * 4;
        float4 v = *(const float4*)&W[(size_t)(k0 + r) * N + n0 + c4];
        Ws[c4 + 0][r] = f2bf(v.x);
        Ws[c4 + 1][r] = f2bf(v.y);
        Ws[c4 + 2][r] = f2bf(v.z);
        Ws[c4 + 3][r] = f2bf(v.w);
    }
    __syncthreads();
    #pragma unroll
    for (int it = 0; it < 2; ++it) {
        const int rn = it * 32 + (tid >> 3);
        const int c8 = (tid & 7) * 8;
        *(short8*)&Wt[(size_t)(n0 + rn) * K + k0 + c8] = *(const short8*)&Ws[rn][c8];
    }
}

// ---------------------------------------------------------------------------
// Proj GEMM: C[M][N] = A[M][K] @ Bt[N][K]^T + bias (fp32 out), m97 structure,
// 1-D grid with XCD-aware bijective swizzle (nwg % 8 == 0).
// ---------------------------------------------------------------------------
__global__ __launch_bounds__(256) void gemm_proj(
    const ushort* __restrict__ A, const ushort* __restrict__ Bt,
    const float* __restrict__ bias, float* __restrict__ C,
    int M, int N, int K)
{
    __shared__ __align__(16) ushort As[128 * 64];
    __shared__ __align__(16) ushort Bs[128 * 64];

    const int nbx = N >> 7;
    const int nwg = (M >> 7) * nbx;
    const int cpx = nwg >> 3;
    const int bid = blockIdx.x;
    const int lb  = (bid & 7) * cpx + (bid >> 3);
    const int n0 = (lb % nbx) * 128;
    const int m0 = (lb / nbx) * 128;

    const int tid = threadIdx.x;
    const int w  = tid >> 6, l = tid & 63;
    const int lr = l & 15,  lg = l >> 4;
    const int wm = w >> 1,  wn = w & 1;

    f32x4 acc[4][4] = {};

    for (int k0 = 0; k0 < K; k0 += 64) {
        #pragma unroll
        for (int i = 0; i < 4; ++i) {
            const int f = i * 256 + w * 64 + l;
            const int r = f >> 3, c = f & 7;
            gload_lds16(A + (size_t)(m0 + r) * K + k0 + ((c ^ (r & 7)) << 3),
                        &As[(i * 256 + w * 64) * 8]);
        }
        #pragma unroll
        for (int i = 0; i < 4; ++i) {
            const int f = i * 256 + w * 64 + l;
            const int r = f >> 3, c = f & 7;
            gload_lds16(Bt + (size_t)(n0 + r) * K + k0 + ((c ^ (r & 7)) << 3),
                        &Bs[(i * 256 + w * 64) * 8]);
        }
        __syncthreads();

        #pragma unroll
        for (int kk = 0; kk < 2; ++kk) {
            short8 a[4], b[4];
            #pragma unroll
            for (int mi = 0; mi < 4; ++mi) {
                const int row = wm * 64 + mi * 16 + lr;
                const int c   = kk * 4 + lg;
                a[mi] = *(const short8*)&As[row * 64 + ((c ^ (row & 7)) << 3)];
            }
            #pragma unroll
            for (int ni = 0; ni < 4; ++ni) {
                const int row = wn * 64 + ni * 16 + lr;
                const int c   = kk * 4 + lg;
                b[ni] = *(const short8*)&Bs[row * 64 + ((c ^ (row & 7)) << 3)];
            }
            #pragma unroll
            for (int mi = 0; mi < 4; ++mi)
                #pragma unroll
                for (int ni = 0; ni < 4; ++ni)
                    acc[mi][ni] = __builtin_amdgcn_mfma_f32_16x16x32_bf16(
                        a[mi], b[ni], acc[mi][ni], 0, 0, 0);
        }
        __syncthreads();
    }

    #pragma unroll
    for (int mi = 0; mi < 4; ++mi) {
        #pragma unroll
        for (int ni = 0; ni < 4; ++ni) {
            const int n = n0 + wn * 64 + ni * 16 + lr;
            const float bv = bias[n];
            #pragma unroll
            for (int j = 0; j < 4; ++j) {
                const int m = m0 + wm * 64 + mi * 16 + lg * 4 + j;
                C[(size_t)m * N + n] = acc[mi][ni][j] + bv;
            }
        }
    }
}

// ---------------------------------------------------------------------------
// Fused QKV GEMM: qkv = xb @ Wqkvt^T + bias, then in-epilogue RoPE + direct
// write to Qb (row-major, *QSCALE), Kswz / Vswz (fragment-major).
// ---------------------------------------------------------------------------
__global__ __launch_bounds__(256) void gemm_qkv_fused(
    const ushort* __restrict__ A,      // xb [4096][1024]
    const ushort* __restrict__ Bt,     // Wqkvt [3072][1024]
    const float*  __restrict__ bias,   // [3072]
    const float2* __restrict__ ctab,   // [2048][32]
    ushort* __restrict__ Qb, ushort* __restrict__ Kswz, ushort* __restrict__ Vswz)
{
    __shared__ __align__(16) ushort As[128 * 64];
    __shared__ __align__(16) ushort Bs[128 * 64];

    const int nbx = QKV_N >> 7;          // 24
    const int cpx = ((BT >> 7) * nbx) >> 3;   // 96
    const int bid = blockIdx.x;
    const int lb  = (bid & 7) * cpx + (bid >> 3);
    const int n0 = (lb % nbx) * 128;
    const int m0 = (lb / nbx) * 128;

    const int tid = threadIdx.x;
    const int w  = tid >> 6, l = tid & 63;
    const int lr = l & 15,  lg = l >> 4;
    const int wm = w >> 1,  wn = w & 1;

    f32x4 acc[4][4] = {};

    for (int k0 = 0; k0 < DD; k0 += 64) {
        #pragma unroll
        for (int i = 0; i < 4; ++i) {
            const int f = i * 256 + w * 64 + l;
            const int r = f >> 3, c = f & 7;
            gload_lds16(A + (size_t)(m0 + r) * DD + k0 + ((c ^ (r & 7)) << 3),
                        &As[(i * 256 + w * 64) * 8]);
        }
        #pragma unroll
        for (int i = 0; i < 4; ++i) {
            const int f = i * 256 + w * 64 + l;
            const int r = f >> 3, c = f & 7;
            gload_lds16(Bt + (size_t)(n0 + r) * DD + k0 + ((c ^ (r & 7)) << 3),
                        &Bs[(i * 256 + w * 64) * 8]);
        }
        __syncthreads();

        #pragma unroll
        for (int kk = 0; kk < 2; ++kk) {
            short8 a[4], b[4];
            #pragma unroll
            for (int mi = 0; mi < 4; ++mi) {
                const int row = wm * 64 + mi * 16 + lr;
                const int c   = kk * 4 + lg;
                a[mi] = *(const short8*)&As[row * 64 + ((c ^ (row & 7)) << 3)];
            }
            #pragma unroll
            for (int ni = 0; ni < 4; ++ni) {
                const int row = wn * 64 + ni * 16 + lr;
                const int c   = kk * 4 + lg;
                b[ni] = *(const short8*)&Bs[row * 64 + ((c ^ (row & 7)) << 3)];
            }
            #pragma unroll
            for (int mi = 0; mi < 4; ++mi)
                #pragma unroll
                for (int ni = 0; ni < 4; ++ni)
                    acc[mi][ni] = __builtin_amdgcn_mfma_f32_16x16x32_bf16(
                        a[mi], b[ni], acc[mi][ni], 0, 0, 0);
        }
        __syncthreads();
    }

    // ---- fused epilogue: bias + RoPE + layout writes ----
    const int g64  = n0 + wn * 64;        // 64-aligned column group
    const int part = g64 >> 10;           // 0=q, 1=k, 2=v  (wave-uniform)
    const int h    = (g64 & 1023) >> 6;

    float bv[4];
    #pragma unroll
    for (int ni = 0; ni < 4; ++ni) bv[ni] = bias[g64 + ni * 16 + lr];

    #pragma unroll
    for (int mi = 0; mi < 4; ++mi) {
        #pragma unroll
        for (int j = 0; j < 4; ++j) {
            const int m  = m0 + wm * 64 + mi * 16 + lg * 4 + j;
            const int bb = m >> 11;
            const int t  = m & (TT - 1);
            const int bh = bb * HH + h;
            const float v0 = acc[mi][0][j] + bv[0];
            const float v1 = acc[mi][1][j] + bv[1];
            const float v2 = acc[mi][2][j] + bv[2];
            const float v3 = acc[mi][3][j] + bv[3];

            if (part == 2) {
                // V: fragment-major (no RoPE)
                ushort* vb = Vswz + (size_t)bh * (TT * HD) + (t >> 6) * 4096
                           + ((t & 63) >> 4) * 512 + ((t >> 3) & 1) * 256
                           + (t & 7) + lr * 8;
                vb[0]    = f2bf(v0);
                vb[128]  = f2bf(v1);
                vb[2048] = f2bf(v2);
                vb[2176] = f2bf(v3);
            } else {
                const float2 cs0 = ctab[t * 32 + lr];
                const float2 cs1 = ctab[t * 32 + 16 + lr];
                float r0 = v0 * cs0.x - v2 * cs0.y;
                float r2 = v0 * cs0.y + v2 * cs0.x;
                float r1 = v1 * cs1.x - v3 * cs1.y;
                float r3 = v1 * cs1.y + v3 * cs1.x;
                if (part == 0) {
                    r0 *= QSCALE; r1 *= QSCALE; r2 *= QSCALE; r3 *= QSCALE;
                    ushort* qb = Qb + (size_t)bh * (TT * HD) + t * HD + lr;
                    qb[0]  = f2bf(r0);
                    qb[16] = f2bf(r1);
                    qb[32] = f2bf(r2);
                    qb[48] = f2bf(r3);
                } else {
                    // K: fragment-major
                    ushort* kb = Kswz + (size_t)bh * (TT * HD) + (t >> 6) * 4096
                               + ((t >> 5) & 1) * 2048 + (t & 31) * 8
                               + ((lr >> 3) & 1) * 256 + (lr & 7);
                    kb[0]    = f2bf(r0);
                    kb[512]  = f2bf(r1);
                    kb[1024] = f2bf(r2);
                    kb[1536] = f2bf(r3);
                }
            }
        }
    }
}

// ---------------------------------------------------------------------------
// Causal flash attention, SPLIT-K: block = one (q-tile, head); its 4 waves
// stride the key tiles (t = w, w+4, ...), each with private (m,l,acc) state,
// then combine via LDS (exact 2^(m_w - M) merge). 2048 blocks = 8192 waves.
// Per-tile body identical to the round-6/7 verified kernel.
// bid&31 = head -> head h pinned to XCD h&7 (K/V L2 locality).
// ---------------------------------------------------------------------------
__global__ __launch_bounds__(256) void attn_splitk(
    const ushort* __restrict__ Qb, const ushort* __restrict__ Kswz,
    const ushort* __restrict__ Vswz, ushort* __restrict__ y)
{
    __shared__ float Lacc[4][32][64];    // [wave][reg][lane] 32 KB
    __shared__ float Lm[4][32], Ll[4][32];

    const int bid = blockIdx.x;
    const int bh  = bid & 31;
    const int qt  = 63 - (bid >> 5);     // big q-tiles dispatch first
    const int b   = bh >> 4;
    const int h   = bh & 15;
    const int tid = threadIdx.x;
    const int w   = tid >> 6;
    const int l   = tid & 63;
    const int lq  = l & 31;
    const int hi  = l >> 5;

    const int wq0 = qt * 32;
    const int qg  = wq0 + lq;            // this lane's q (softmax state owner)

    const ushort* Kbh = Kswz + (size_t)bh * TT * HD;
    const ushort* Vbh = Vswz + (size_t)bh * TT * HD;

    // Q fragments (B-operand), 4 d-chunks of 16
    short8 qf[4];
    {
        const ushort* qrow = Qb + ((size_t)bh * TT + qg) * HD + hi * 8;
        #pragma unroll
        for (int dc = 0; dc < 4; ++dc)
            qf[dc] = *(const short8*)(qrow + dc * 16);
    }

    f32x16 acc0 = {}, acc1 = {};         // O^T partial: [d=lq | d=lq+32][16 q]
    float m = -1e30f, lsum = 0.0f;

    const int nt = (wq0 >> 6) + 1;       // total 64-key tiles for this q-tile

    for (int t = w; t < nt; t += 4) {
        const int k0 = t * 64;
        const ushort* kb = Kbh + (size_t)t * 4096 + l * 8;
        const ushort* vb = Vbh + (size_t)t * 4096 + l * 8;

        // ---- fully-coalesced fragment loads (1KB streams) ----
        short8 kf0[4], kf1[4], vf0[4], vf1[4];
        #pragma unroll
        for (int dc = 0; dc < 4; ++dc) {
            kf0[dc] = *(const short8*)(kb + dc * 512);
            kf1[dc] = *(const short8*)(kb + (4 + dc) * 512);
            vf0[dc] = *(const short8*)(vb + dc * 512);
            vf1[dc] = *(const short8*)(vb + (4 + dc) * 512);
        }

        // ---- S^T = K @ Q^T : lane holds 32 keys for q = qg (log2 units) ----
        f32x16 st0 = {}, st1 = {};
        __builtin_amdgcn_s_setprio(1);
        #pragma unroll
        for (int dc = 0; dc < 4; ++dc) {
            st0 = mfma32(kf0[dc], qf[dc], st0);
            st1 = mfma32(kf1[dc], qf[dc], st1);
        }
        __builtin_amdgcn_s_setprio(0);

        // ---- causal mask (only diagonal tile) ----
        if (t == nt - 1) {
            #pragma unroll
            for (int r = 0; r < 16; ++r) {
                const int kk = k0 + (r & 3) + 8 * (r >> 2) + 4 * hi;
                if (kk > qg)      st0[r] = -1e30f;
                if (kk + 32 > qg) st1[r] = -1e30f;
            }
        }

        // ---- row max: tree + one shfl ----
        float pm;
        {
            float m16[16];
            #pragma unroll
            for (int i = 0; i < 16; ++i) m16[i] = fmaxf(st0[i], st1[i]);
            float m8[8];
            #pragma unroll
            for (int i = 0; i < 8; ++i) m8[i] = fmaxf(m16[i], m16[i + 8]);
            const float a = fmaxf(fmaxf(m8[0], m8[4]), fmaxf(m8[1], m8[5]));
            const float c = fmaxf(fmaxf(m8[2], m8[6]), fmaxf(m8[3], m8[7]));
            pm = fmaxf(a, c);
        }
        pm = fmaxf(pm, __shfl_xor(pm, 32));

        // ---- defer-max: rescale only when max grew past threshold ----
        if (!__all(pm - m <= 8.0f)) {
            const float nm    = fmaxf(m, pm);
            const float alpha = fexp2(m - nm);
            m = nm;
            lsum *= alpha;
            #pragma unroll
            for (int r = 0; r < 16; ++r) {
                const float ar = __shfl(alpha, (r & 3) + 8 * (r >> 2) + 4 * hi);
                acc0[r] *= ar; acc1[r] *= ar;
            }
        }

        // ---- exp2 + tree sum ----
        #pragma unroll
        for (int r = 0; r < 16; ++r) {
            st0[r] = fexp2(st0[r] - m);
            st1[r] = fexp2(st1[r] - m);
        }
        float rs;
        {
            float s16[16];
            #pragma unroll
            for (int i = 0; i < 16; ++i) s16[i] = st0[i] + st1[i];
            float s8[8];
            #pragma unroll
            for (int i = 0; i < 8; ++i) s8[i] = s16[i] + s16[i + 8];
            rs = ((s8[0] + s8[4]) + (s8[1] + s8[5]))
               + ((s8[2] + s8[6]) + (s8[3] + s8[7]));
        }
        rs += __shfl_xor(rs, 32);
        lsum += rs;

        // ---- pack P -> bf16 A-fragments via cvt_pk + permlane32_swap ----
        short8 pfr[4];
        #pragma unroll
        for (int sub = 0; sub < 2; ++sub) {
            const f32x16& ps = sub ? st1 : st0;
            uint32_t A0 = cvtpk_bf16(ps[0],  ps[1]);
            uint32_t A1 = cvtpk_bf16(ps[2],  ps[3]);
            uint32_t B0 = cvtpk_bf16(ps[4],  ps[5]);
            uint32_t B1 = cvtpk_bf16(ps[6],  ps[7]);
            uint32_t C0 = cvtpk_bf16(ps[8],  ps[9]);
            uint32_t C1 = cvtpk_bf16(ps[10], ps[11]);
            uint32_t D0 = cvtpk_bf16(ps[12], ps[13]);
            uint32_t D1 = cvtpk_bf16(ps[14], ps[15]);
            pl32swap(A0, B0); pl32swap(A1, B1);
            pl32swap(C0, D0); pl32swap(C1, D1);
            union { uint32_t u[4]; short8 s; } f0, f1;
            f0.u[0] = A0; f0.u[1] = A1; f0.u[2] = B0; f0.u[3] = B1;
            f1.u[0] = C0; f1.u[1] = C1; f1.u[2] = D0; f1.u[3] = D1;
            pfr[sub * 2]     = f0.s;
            pfr[sub * 2 + 1] = f1.s;
        }

        // ---- PV: O += P @ V ----
        __builtin_amdgcn_s_setprio(1);
        #pragma unroll
        for (int kc = 0; kc < 4; ++kc) {
            acc0 = mfma32(pfr[kc], vf0[kc], acc0);
            acc1 = mfma32(pfr[kc], vf1[kc], acc1);
        }
        __builtin_amdgcn_s_setprio(0);
    }

    // ---- write partials to LDS (lane-contiguous, conflict-free) ----
    #pragma unroll
    for (int r = 0; r < 16; ++r) {
        Lacc[w][r][l]      = acc0[r];
        Lacc[w][r + 16][l] = acc1[r];
    }
    if (hi == 0) { Lm[w][lq] = m; Ll[w][lq] = lsum; }
    __syncthreads();

    // ---- combine: wave w merges storage regs r in [8w, 8w+8) ----
    const int r0 = w * 8;
    float invL[8], alf[8][4];
    #pragma unroll
    for (int i = 0; i < 8; ++i) {
        const int rr  = (r0 + i) & 15;
        const int row = (rr & 3) + 8 * (rr >> 2) + 4 * hi;
        const float m0v = Lm[0][row], m1v = Lm[1][row];
        const float m2v = Lm[2][row], m3v = Lm[3][row];
        const float M = fmaxf(fmaxf(m0v, m1v), fmaxf(m2v, m3v));
        const float a0 = fexp2(m0v - M), a1 = fexp2(m1v - M);
        const float a2 = fexp2(m2v - M), a3 = fexp2(m3v - M);
        const float L = Ll[0][row] * a0 + Ll[1][row] * a1
                      + Ll[2][row] * a2 + Ll[3][row] * a3;
        invL[i] = 1.0f / L;
        alf[i][0] = a0; alf[i][1] = a1; alf[i][2] = a2; alf[i][3] = a3;
    }
    #pragma unroll
    for (int i = 0; i < 8; ++i) {
        const int r   = r0 + i;
        const int rr  = r & 15;
        const int row = (rr & 3) + 8 * (rr >> 2) + 4 * hi;
        float o = Lacc[0][r][l] * alf[i][0] + Lacc[1][r][l] * alf[i][1]
                + Lacc[2][r][l] * alf[i][2] + Lacc[3][r][l] * alf[i][3];
        o *= invL[i];
        const int d = (r < 16) ? lq : (32 + lq);
        y[((size_t)b * TT + wq0 + row) * DD + h * HD + d] = f2bf(o);
    }
}

// ---------------------------------------------------------------------------
extern "C" void kernel_launch(void* const* d_in, const int* in_sizes, int n_in,
                              void* d_out, int out_size, void* d_ws, size_t ws_size,
                              hipStream_t stream)
{
    const float* x     = (const float*)d_in[0];   // [B,T,D]
    const float* Wqkv  = (const float*)d_in[1];   // [D, 3D]
    const float* bqkv  = (const float*)d_in[2];   // [3D]
    const float* Wproj = (const float*)d_in[3];   // [D, D]
    const float* bproj = (const float*)d_in[4];   // [D]
    float* out = (float*)d_out;                   // [B,T,D]

    ushort* yb     = (ushort*)d_ws;
    ushort* Qb     = yb     + (size_t)BT * DD;
    ushort* Kswz   = Qb     + (size_t)BB * HH * TT * HD;
    ushort* Vswz   = Kswz   + (size_t)BB * HH * TT * HD;
    ushort* xb     = Vswz   + (size_t)BB * HH * TT * HD;
    ushort* Wqkvt  = xb     + (size_t)BT * DD;
    ushort* Wprojt = Wqkvt  + (size_t)QKV_N * DD;
    float2* ctab   = (float2*)(Wprojt + (size_t)DD * DD);

    // 0) conversions + tables
    f32_to_bf16<<<(BT * DD / 8 + 255) / 256, 256, 0, stream>>>(x, xb, BT * DD / 8);
    rope_tab<<<TT * 32 / 256, 256, 0, stream>>>(ctab);
    {
        dim3 g1(QKV_N / 64, DD / 64);
        transpose_w_bf16<<<g1, 256, 0, stream>>>(Wqkv, Wqkvt, DD, QKV_N);
        dim3 g2(DD / 64, DD / 64);
        transpose_w_bf16<<<g2, 256, 0, stream>>>(Wproj, Wprojt, DD, DD);
    }
    // 1) Fused QKV GEMM + bias + RoPE + layout (writes Qb/Kswz/Vswz directly)
    {
        gemm_qkv_fused<<<(BT / 128) * (QKV_N / 128), 256, 0, stream>>>(
            xb, Wqkvt, bqkv, ctab, Qb, Kswz, Vswz);
    }
    // 2) Causal attention, split-K over 4 waves/block, LDS combine
    {
        attn_splitk<<<2048, 256, 0, stream>>>(Qb, Kswz, Vswz, yb);
    }
    // 3) Output projection (bf16 MFMA, fp32 out), XCD-swizzled
    {
        gemm_proj<<<(BT / 128) * (DD / 128), 256, 0, stream>>>(
            yb, Wprojt, bproj, out, BT, DD, DD);
    }
}